// Round 4
// baseline (693.727 us; speedup 1.0000x reference)
//
#include <hip/hip_runtime.h>
#include <stdint.h>
#include <math.h>

typedef __attribute__((ext_vector_type(8))) short short8;
typedef __attribute__((ext_vector_type(4))) short short4v;
typedef __attribute__((ext_vector_type(4))) float floatx4;

#define DEV static __device__ __forceinline__

DEV float bf2f(unsigned short u){ union { unsigned int i; float f; } c; c.i = ((unsigned int)u) << 16; return c.f; }
DEV unsigned short f2bf(float f){ union { float f; unsigned int i; } c; c.f = f; unsigned int u = c.i; u += 0x7fffu + ((u >> 16) & 1u); return (unsigned short)(u >> 16); }

#if defined(__has_builtin)
#if __has_builtin(__builtin_amdgcn_global_load_lds)
#define USE_GLL 1
#endif
#endif
#ifndef USE_GLL
#define USE_GLL 0
#endif

// async global->LDS, 16B per lane. ldsbase is wave-uniform; HW writes base + lane*16.
DEV void gll16(const unsigned short* g, unsigned short* ldsbase, int lane){
#if USE_GLL
  __builtin_amdgcn_global_load_lds((const __attribute__((address_space(1))) void*)g,
                                   (__attribute__((address_space(3))) void*)ldsbase, 16, 0, 0);
#else
  *(short8*)(ldsbase + lane * 8) = *(const short8*)g;
#endif
}

DEV void atomAddF(float* p, float v){
  __hip_atomic_fetch_add(p, v, __ATOMIC_RELAXED, __HIP_MEMORY_SCOPE_AGENT);
}
DEV void atomAddD(double* p, double v){
  __hip_atomic_fetch_add(p, v, __ATOMIC_RELAXED, __HIP_MEMORY_SCOPE_AGENT);
}

// -------- transpose + convert: out_bf16[C][R] = in_f32[R][C], batched over blockIdx.z ----
__global__ __launch_bounds__(256) void k_transpose(const float* __restrict__ in,
                                                   unsigned short* __restrict__ out,
                                                   int R, int C)
{
  __shared__ unsigned short tile[64 * 68];
  const int tid = threadIdx.x;
  const long boff = (long)blockIdx.z * (long)R * (long)C;
  in += boff; out += boff;
  const int c0 = blockIdx.x * 64, r0 = blockIdx.y * 64;
  const int rr = tid >> 4;
  const int c4 = (tid & 15) * 4;
#pragma unroll
  for (int i = 0; i < 4; i++){
    int r = rr + i * 16;
    floatx4 v = *(const floatx4*)(in + (long)(r0 + r) * C + c0 + c4);
#pragma unroll
    for (int u = 0; u < 4; u++) tile[r * 68 + c4 + u] = f2bf(v[u]);
  }
  __syncthreads();
#pragma unroll
  for (int i = 0; i < 4; i++){
    int cc = rr + i * 16;
    short4v v;
#pragma unroll
    for (int u = 0; u < 4; u++) v[u] = (short)tile[(c4 + u) * 68 + cc];
    *(short4v*)(out + (long)(c0 + cc) * R + r0 + c4) = v;
  }
}

// -------- elementwise convert: bf16 copy of x ---------------------------------------------
__global__ __launch_bounds__(256) void k_xconv(const float* __restrict__ xf,
                                               unsigned short* __restrict__ xb)
{
  const long i = ((long)blockIdx.x * 256 + threadIdx.x) * 4;
  floatx4 v = *(const floatx4*)(xf + i);
  short4v o;
#pragma unroll
  for (int u = 0; u < 4; u++) o[u] = (short)f2bf(v[u]);
  *(short4v*)(xb + i) = o;
}

// -------- fold: W[d][h*24+e] = sum_dh head[d][h*128+dh]*choice[e][dh]  (fp64) -------------
__global__ __launch_bounds__(128) void k_fold(const float* __restrict__ head,
                                              const float* __restrict__ choice,
                                              double* __restrict__ W)
{
  __shared__ double hrow[768];
  const int d = blockIdx.x;
  for (int i = threadIdx.x; i < 768; i += 128) hrow[i] = (double)head[(long)d * 768 + i];
  __syncthreads();
  for (int c = threadIdx.x; c < 144; c += 128){
    int h = c / 24, e = c % 24;
    double a = 0.0;
    const double* hr = hrow + h * 128;
    const float* ch = choice + e * 128;
#pragma unroll 8
    for (int k = 0; k < 128; k++) a += hr[k] * (double)ch[k];
    W[(long)d * 144 + c] = a;
  }
}

// -------- gates matmul: logits64[8192][144] += x[64-row tile] @ W[k-seg]  (fp64) ----------
// grid (128 row-tiles, 4 k-segments of 192). block 256 = 16 tx (9 cols) x 16 ty (4 rows).
__global__ __launch_bounds__(256, 2) void k_gates_mm(const float* __restrict__ xg,
                                                     const double* __restrict__ W,
                                                     double* __restrict__ logits64)
{
  __shared__ float  xs[32 * 64];    // [kk][row] fp32, 8 KB
  __shared__ double Ws[32 * 144];   // [kk][c]  fp64, 36 KB
  const int tid = threadIdx.x;
  const int tx = tid & 15;          // cols c = tx + 16j, j<9
  const int ty = tid >> 4;          // rows = ty*4 + i, i<4
  const int row0 = blockIdx.x * 64;
  const int kseg = blockIdx.y * 192;

  double acc[4][9];
#pragma unroll
  for (int i = 0; i < 4; i++)
#pragma unroll
    for (int j = 0; j < 9; j++) acc[i][j] = 0.0;

  for (int kc = 0; kc < 192; kc += 32){
    const int k0 = kseg + kc;
    {
      int rr = tid & 63;                 // row
      int kk8 = (tid >> 6) * 8;          // 0,8,16,24
      const float* src = xg + (long)(row0 + rr) * 768 + k0 + kk8;
      floatx4 v0 = *(const floatx4*)src;
      floatx4 v1 = *(const floatx4*)(src + 4);
#pragma unroll
      for (int u = 0; u < 4; u++) xs[(kk8 + u) * 64 + rr] = v0[u];
#pragma unroll
      for (int u = 0; u < 4; u++) xs[(kk8 + 4 + u) * 64 + rr] = v1[u];
    }
    for (int f = tid; f < 4608; f += 256) Ws[f] = W[(long)(k0 + f / 144) * 144 + (f % 144)];
    __syncthreads();
#pragma unroll 2
    for (int kk = 0; kk < 32; kk++){
      floatx4 xv = *(const floatx4*)&xs[kk * 64 + ty * 4];
      double xd[4];
#pragma unroll
      for (int i = 0; i < 4; i++) xd[i] = (double)xv[i];
#pragma unroll
      for (int j = 0; j < 9; j++){
        double wv = Ws[kk * 144 + tx + 16 * j];
#pragma unroll
        for (int i = 0; i < 4; i++) acc[i][j] += xd[i] * wv;
      }
    }
    __syncthreads();
  }
#pragma unroll
  for (int i = 0; i < 4; i++){
    double* dst = logits64 + (long)(row0 + ty * 4 + i) * 144;
#pragma unroll
    for (int j = 0; j < 9; j++) atomAddD(dst + tx + 16 * j, acc[i][j]);
  }
}

// -------- softmax over 24 experts per (token,head); write transposed gatesT[be][n] --------
__global__ __launch_bounds__(256) void k_softmax(const double* __restrict__ logits64,
                                                 double* __restrict__ gatesT)
{
  const int gid = blockIdx.x * 256 + threadIdx.x;   // < 49152
  const int R = gid / 6, h = gid % 6;
  const int b = R >> 10, s = R & 1023;
  const int n = s * 6 + h;
  const double* base = logits64 + (long)R * 144 + h * 24;
  double m = base[0];
  for (int e = 1; e < 24; e++) m = fmax(m, base[e]);
  double ssum = 0.0;
  for (int e = 0; e < 24; e++) ssum += exp(base[e] - m);
  double is = 1.0 / ssum;
  for (int e = 0; e < 24; e++)
    gatesT[((long)(b * 24 + e)) * 6144 + n] = exp(base[e] - m) * is;
}

// -------- top-K=1024 of 6144 per (b,e), exact fp64, jax tie semantics ---------------------
DEV int blk_reduce(int v, volatile int* sbuf, int tid){
#pragma unroll
  for (int off = 32; off > 0; off >>= 1) v += __shfl_down(v, off);
  __syncthreads();
  if ((tid & 63) == 0) sbuf[tid >> 6] = v;
  __syncthreads();
  return sbuf[0] + sbuf[1] + sbuf[2] + sbuf[3];
}

__global__ __launch_bounds__(256) void k_topk(const double* __restrict__ gatesT,
                                              int* __restrict__ Kidx, float* __restrict__ Gval)
{
  __shared__ int sbuf[4];
  __shared__ int s_pos;
  const int tid = threadIdx.x;
  const int be = blockIdx.x;
  const double* g = gatesT + (long)be * 6144;

  unsigned long long key[24];
#pragma unroll
  for (int j = 0; j < 24; j++)
    key[j] = (unsigned long long)__double_as_longlong(g[tid + 256 * j]);

  unsigned long long lo = 0ull, hi = ~0ull;
  for (int it = 0; it < 64; ++it){
    if (hi - lo <= 1ull) break;
    unsigned long long mid = lo + ((hi - lo) >> 1);
    int c = 0;
#pragma unroll
    for (int j = 0; j < 24; j++) c += (key[j] > mid) ? 1 : 0;
    c = blk_reduce(c, sbuf, tid);
    if (c >= 1024) lo = mid; else hi = mid;
  }
  const unsigned long long T = hi;
  int cg = 0;
#pragma unroll
  for (int j = 0; j < 24; j++) cg += (key[j] > T) ? 1 : 0;
  cg = blk_reduce(cg, sbuf, tid);
  const int need = 1024 - cg;

  int lo2 = 0, hi2 = 6144;
  for (int it = 0; it < 13; ++it){
    if (hi2 - lo2 <= 1) break;
    int mid = (lo2 + hi2) >> 1;
    int c = 0;
#pragma unroll
    for (int j = 0; j < 24; j++) c += (key[j] == T && (tid + 256 * j) < mid) ? 1 : 0;
    c = blk_reduce(c, sbuf, tid);
    if (c >= need) hi2 = mid; else lo2 = mid;
  }
  const int m = hi2;

  if (tid == 0) s_pos = 0;
  __syncthreads();
#pragma unroll
  for (int j = 0; j < 24; j++){
    int n = tid + 256 * j;
    bool sel = (key[j] > T) || (key[j] == T && n < m);
    if (sel){
      int slot = atomicAdd(&s_pos, 1);
      Kidx[(long)be * 1024 + slot] = n;
      Gval[(long)be * 1024 + slot] = (float)__longlong_as_double((long long)key[j]);
    }
  }
}

// -------- bf16 MFMA GEMM (BT input), 128x128 tile, BK=64; OUTF=1 -> fp32 C ----------------
template<int OUTF>
__global__ __launch_bounds__(256, 2) void k_gemm(const unsigned short* __restrict__ A,
    const unsigned short* __restrict__ BT, unsigned short* __restrict__ C,
    float* __restrict__ Cf, int M, int N, int K)
{
  __shared__ unsigned short As[128 * 64];
  __shared__ unsigned short Bs[128 * 64];
  const int tid = threadIdx.x;
  const int lane = tid & 63;
  const int w = tid >> 6;
  const int wy = w >> 1, wx = w & 1;
  const int m0 = blockIdx.x * 128;
  const int n0 = blockIdx.y * 128;

  floatx4 acc[4][4];
  {
    floatx4 z4 = {0.f, 0.f, 0.f, 0.f};
#pragma unroll
    for (int i = 0; i < 4; i++)
#pragma unroll
      for (int j = 0; j < 4; j++) acc[i][j] = z4;
  }

  const int rsub = lane >> 3;
  const int kcol = (lane & 7) * 8;

  for (int k0 = 0; k0 < K; k0 += 64){
#pragma unroll
    for (int i = 0; i < 4; i++){
      const int inst = w * 4 + i;
      const int rr = inst * 8 + rsub;
      gll16(A + (long)(m0 + rr) * K + k0 + kcol, &As[inst * 512], lane);
      gll16(BT + (long)(n0 + rr) * K + k0 + kcol, &Bs[inst * 512], lane);
    }
    __syncthreads();
#pragma unroll
    for (int ks = 0; ks < 2; ++ks){
      const int kb = ks * 32 + (lane >> 4) * 8;
      short8 af[4], bfr[4];
#pragma unroll
      for (int mi = 0; mi < 4; mi++) af[mi]  = *(const short8*)&As[(wy * 64 + mi * 16 + (lane & 15)) * 64 + kb];
#pragma unroll
      for (int ni = 0; ni < 4; ni++) bfr[ni] = *(const short8*)&Bs[(wx * 64 + ni * 16 + (lane & 15)) * 64 + kb];
#pragma unroll
      for (int mi = 0; mi < 4; mi++)
#pragma unroll
        for (int ni = 0; ni < 4; ni++)
          acc[mi][ni] = __builtin_amdgcn_mfma_f32_16x16x32_bf16(af[mi], bfr[ni], acc[mi][ni], 0, 0, 0);
    }
    __syncthreads();
  }

  const int ml = lane & 15;
  const int rq = (lane >> 4) * 4;
#pragma unroll
  for (int mi = 0; mi < 4; mi++){
    const int rowb = m0 + wy * 64 + mi * 16 + rq;
#pragma unroll
    for (int ni = 0; ni < 4; ni++){
      const int col = n0 + wx * 64 + ni * 16 + ml;
#pragma unroll
      for (int r = 0; r < 4; r++){
        float v = acc[mi][ni][r];
        if (OUTF) Cf[(long)(rowb + r) * N + col] = v;
        else      C[(long)(rowb + r) * N + col] = f2bf(v);
      }
    }
  }
}

// -------- fused per-expert FFN: scatter(gate * (silu(gather(x1)@w1) @ w2)) into xacc ------
// grid (16 m-tiles of 64 rows, 192 be). block 256. LDS 56 KB -> 2 blocks/CU.
__global__ __launch_bounds__(256, 2) void k_ffn(const unsigned short* __restrict__ x1,
    const unsigned short* __restrict__ w1T, const unsigned short* __restrict__ w2T,
    const int* __restrict__ KidxAll, const float* __restrict__ GvalAll,
    float* __restrict__ xacc)
{
  __shared__ unsigned short As[64 * 128];    // 16 KB [row][k]
  __shared__ unsigned short W1c[64 * 128];   // 16 KB [hcol][k]
  __shared__ unsigned short W2c[128 * 64];   // 16 KB [out][kchunk]
  __shared__ unsigned short Hc[64 * 64];     //  8 KB [row][hcol]
  const int tid = threadIdx.x, lane = tid & 63, w = tid >> 6;
  const int mt = blockIdx.x;
  const int be = blockIdx.y;
  const int b = be / 24, e = be % 24;
  const int* idx = KidxAll + (long)be * 1024 + mt * 64;
  const float* scl = GvalAll + (long)be * 1024 + mt * 64;
  const unsigned short* A   = x1  + (long)b * 6144 * 128;
  const unsigned short* w1e = w1T + (long)e * 384 * 128;
  const unsigned short* w2e = w2T + (long)e * 128 * 384;

  // stage As: 64 rows x 128 k (gathered). wave w: rows w*16..+16, 4 instrs x 4 rows.
  {
    const int r0 = w * 16;
#pragma unroll
    for (int i = 0; i < 4; i++){
      int rr = r0 + i * 4 + (lane >> 4);
      gll16(A + (long)idx[rr] * 128 + (lane & 15) * 8, &As[(r0 + i * 4) * 128], lane);
    }
  }

  floatx4 Yt[2][4];
  {
    floatx4 z4 = {0.f, 0.f, 0.f, 0.f};
#pragma unroll
    for (int i = 0; i < 2; i++)
#pragma unroll
      for (int j = 0; j < 4; j++) Yt[i][j] = z4;
  }

  for (int nc = 0; nc < 6; ++nc){
    {  // stage W1c: hcols nc*64..+64, full K=128
      const int r0 = w * 16;
#pragma unroll
      for (int i = 0; i < 4; i++){
        int rr = nc * 64 + r0 + i * 4 + (lane >> 4);
        gll16(w1e + (long)rr * 128 + (lane & 15) * 8, &W1c[(r0 + i * 4) * 128], lane);
      }
    }
    {  // stage W2c: all 128 outs, k-cols nc*64..+64; 4 instrs x 8 rows per wave
      const int r0 = w * 32;
#pragma unroll
      for (int i = 0; i < 4; i++){
        int rr = r0 + i * 8 + (lane >> 3);
        gll16(w2e + (long)rr * 384 + nc * 64 + (lane & 7) * 8, &W2c[(r0 + i * 8) * 64], lane);
      }
    }
    __syncthreads();   // staging done (and, transitively, prev iter's stage2 done)

    // stage1: h chunk, wave w -> token rows w*16..+16 x 64 hcols
    floatx4 h4[4];
    {
      floatx4 z4 = {0.f, 0.f, 0.f, 0.f};
#pragma unroll
      for (int j = 0; j < 4; j++) h4[j] = z4;
    }
#pragma unroll
    for (int ks = 0; ks < 4; ++ks){
      short8 af = *(const short8*)&As[(w * 16 + (lane & 15)) * 128 + ks * 32 + (lane >> 4) * 8];
#pragma unroll
      for (int nf = 0; nf < 4; ++nf){
        short8 bfr = *(const short8*)&W1c[(nf * 16 + (lane & 15)) * 128 + ks * 32 + (lane >> 4) * 8];
        h4[nf] = __builtin_amdgcn_mfma_f32_16x16x32_bf16(af, bfr, h4[nf], 0, 0, 0);
      }
    }
    // silu -> Hc  (C layout: col=lane&15, row=(lane>>4)*4+r)
#pragma unroll
    for (int nf = 0; nf < 4; ++nf){
#pragma unroll
      for (int r = 0; r < 4; r++){
        float v = h4[nf][r];
        v = v / (1.f + __expf(-v));
        Hc[(w * 16 + (lane >> 4) * 4 + r) * 64 + nf * 16 + (lane & 15)] = f2bf(v);
      }
    }
    __syncthreads();   // Hc visible

    // stage2: YaccT[out][row] += W2c[out][k] (A) x Hc[row][k] (B); wave w -> outs w*32..+32
#pragma unroll
    for (int ks = 0; ks < 2; ++ks){
      short8 a2[2], b2[4];
#pragma unroll
      for (int mf = 0; mf < 2; ++mf)
        a2[mf] = *(const short8*)&W2c[(w * 32 + mf * 16 + (lane & 15)) * 64 + ks * 32 + (lane >> 4) * 8];
#pragma unroll
      for (int nf = 0; nf < 4; ++nf)
        b2[nf] = *(const short8*)&Hc[(nf * 16 + (lane & 15)) * 64 + ks * 32 + (lane >> 4) * 8];
#pragma unroll
      for (int mf = 0; mf < 2; ++mf)
#pragma unroll
        for (int nf = 0; nf < 4; ++nf)
          Yt[mf][nf] = __builtin_amdgcn_mfma_f32_16x16x32_bf16(a2[mf], b2[nf], Yt[mf][nf], 0, 0, 0);
    }
    __syncthreads();   // stage2 done; safe to overwrite W1c/W2c/Hc next iter
  }

  // epilogue: YaccT element (out = w*32+mf*16+(lane>>4)*4+r, row = nf*16+(lane&15))
#pragma unroll
  for (int nf = 0; nf < 4; ++nf){
    const int rb = nf * 16 + (lane & 15);
    const int n = idx[rb];
    const float g = scl[rb];
    float* dst = xacc + ((long)b * 6144 + n) * 128;
#pragma unroll
    for (int mf = 0; mf < 2; ++mf){
      const int ob = w * 32 + mf * 16 + (lane >> 4) * 4;
#pragma unroll
      for (int r = 0; r < 4; r++)
        atomAddF(dst + ob + r, Yt[mf][nf][r] * g);
    }
  }
}

// -------- convert fp32 accumulator -> bf16 token matrix -----------------------------------
__global__ __launch_bounds__(256) void k_convert(const float* __restrict__ xa,
                                                 unsigned short* __restrict__ xo)
{
  const long i = ((long)blockIdx.x * 256 + threadIdx.x) * 4;
  floatx4 v = *(const floatx4*)(xa + i);
  short4v o;
#pragma unroll
  for (int u = 0; u < 4; u++) o[u] = (short)f2bf(v[u]);
  *(short4v*)(xo + i) = o;
}

// ==========================================================================================
extern "C" void kernel_launch(void* const* d_in, const int* in_sizes, int n_in,
                              void* d_out, int out_size, void* d_ws, size_t ws_size,
                              hipStream_t stream)
{
  const float* x      = (const float*)d_in[0];
  const float* choice = (const float*)d_in[1];
  const float* w1     = (const float*)d_in[2];
  const float* w2     = (const float*)d_in[3];
  const float* head   = (const float*)d_in[4];
  const float* merge  = (const float*)d_in[5];
  float* out = (float*)d_out;
  (void)in_sizes; (void)n_in; (void)out_size; (void)ws_size;

  char* p = (char*)d_ws;
  auto alloc = [&p](size_t bytes) -> void* {
    void* q = (void*)p; p += (bytes + 255) & ~(size_t)255; return q;
  };

  unsigned short* headT = (unsigned short*)alloc((size_t)768 * 768 * 2);
  unsigned short* mergeT= (unsigned short*)alloc((size_t)768 * 768 * 2);
  unsigned short* w1T   = (unsigned short*)alloc((size_t)24 * 384 * 128 * 2);
  unsigned short* w2T   = (unsigned short*)alloc((size_t)24 * 128 * 384 * 2);
  double* W64           = (double*)alloc((size_t)768 * 144 * 8);
  int* Kidx             = (int*)alloc((size_t)192 * 1024 * 4);
  float* Gval           = (float*)alloc((size_t)192 * 1024 * 4);
  unsigned short* xb    = (unsigned short*)alloc((size_t)8192 * 768 * 2);   // 12.58 MB
  double* gatesT        = (double*)xb;   // 9.44 MB; live after xb's last read (gemm0)
  unsigned short* xout  = xb;            // live after gatesT dead (post-topk)
  unsigned short* x1    = (unsigned short*)alloc((size_t)8192 * 768 * 2);   // 12.58 MB
  double* logits64      = (double*)alloc((size_t)8192 * 144 * 8);           //  9.44 MB
  float* xacc           = out;           // fp32 scatter accumulator lives in d_out

  hipMemsetAsync(logits64, 0, (size_t)8192 * 144 * 8, stream);
  hipMemsetAsync(xacc, 0, (size_t)8192 * 768 * 4, stream);
  k_transpose<<<dim3(12, 12, 1), 256, 0, stream>>>(head, headT, 768, 768);
  k_transpose<<<dim3(12, 12, 1), 256, 0, stream>>>(merge, mergeT, 768, 768);
  k_transpose<<<dim3(6, 2, 24), 256, 0, stream>>>(w1, w1T, 128, 384);
  k_transpose<<<dim3(2, 6, 24), 256, 0, stream>>>(w2, w2T, 384, 128);
  k_fold<<<dim3(768), 128, 0, stream>>>(head, choice, W64);
  k_xconv<<<dim3(6144), 256, 0, stream>>>(x, xb);
  k_gemm<0><<<dim3(64, 6, 1), 256, 0, stream>>>(xb, headT, x1, nullptr, 8192, 768, 768);
  // xb dead -> gatesT region usable
  k_gates_mm<<<dim3(128, 4, 1), 256, 0, stream>>>(x, W64, logits64);
  k_softmax<<<dim3(192), 256, 0, stream>>>(logits64, gatesT);
  k_topk<<<dim3(192), 256, 0, stream>>>(gatesT, Kidx, Gval);
  // gatesT dead after topk
  k_ffn<<<dim3(16, 192, 1), 256, 0, stream>>>(x1, w1T, w2T, Kidx, Gval, xacc);
  k_convert<<<dim3(6144), 256, 0, stream>>>(xacc, xout);
  k_gemm<1><<<dim3(64, 6, 1), 256, 0, stream>>>(xout, mergeT, nullptr, out, 8192, 768, 768);
}

// Round 5
// 604.514 us; speedup vs baseline: 1.1476x; 1.1476x over previous
//
#include <hip/hip_runtime.h>
#include <stdint.h>
#include <math.h>

typedef __attribute__((ext_vector_type(8))) short short8;
typedef __attribute__((ext_vector_type(4))) short short4v;
typedef __attribute__((ext_vector_type(4))) float floatx4;
typedef __attribute__((ext_vector_type(2))) float floatx2;

#define DEV static __device__ __forceinline__

DEV float bf2f(unsigned short u){ union { unsigned int i; float f; } c; c.i = ((unsigned int)u) << 16; return c.f; }
DEV unsigned short f2bf(float f){ union { float f; unsigned int i; } c; c.f = f; unsigned int u = c.i; u += 0x7fffu + ((u >> 16) & 1u); return (unsigned short)(u >> 16); }

#if defined(__has_builtin)
#if __has_builtin(__builtin_amdgcn_global_load_lds)
#define USE_GLL 1
#endif
#endif
#ifndef USE_GLL
#define USE_GLL 0
#endif

// async global->LDS, 16B per lane. ldsbase is wave-uniform; HW writes base + lane*16.
DEV void gll16(const unsigned short* g, unsigned short* ldsbase, int lane){
#if USE_GLL
  __builtin_amdgcn_global_load_lds((const __attribute__((address_space(1))) void*)g,
                                   (__attribute__((address_space(3))) void*)ldsbase, 16, 0, 0);
#else
  *(short8*)(ldsbase + lane * 8) = *(const short8*)g;
#endif
}

// -------- transpose + convert: out_bf16[C][R] = in_f32[R][C], batched over blockIdx.z ----
__global__ __launch_bounds__(256) void k_transpose(const float* __restrict__ in,
                                                   unsigned short* __restrict__ out,
                                                   int R, int C)
{
  __shared__ unsigned short tile[64 * 68];
  const int tid = threadIdx.x;
  const long boff = (long)blockIdx.z * (long)R * (long)C;
  in += boff; out += boff;
  const int c0 = blockIdx.x * 64, r0 = blockIdx.y * 64;
  const int rr = tid >> 4;
  const int c4 = (tid & 15) * 4;
#pragma unroll
  for (int i = 0; i < 4; i++){
    int r = rr + i * 16;
    floatx4 v = *(const floatx4*)(in + (long)(r0 + r) * C + c0 + c4);
#pragma unroll
    for (int u = 0; u < 4; u++) tile[r * 68 + c4 + u] = f2bf(v[u]);
  }
  __syncthreads();
#pragma unroll
  for (int i = 0; i < 4; i++){
    int cc = rr + i * 16;
    short4v v;
#pragma unroll
    for (int u = 0; u < 4; u++) v[u] = (short)tile[(c4 + u) * 68 + cc];
    *(short4v*)(out + (long)(c0 + cc) * R + r0 + c4) = v;
  }
}

// -------- elementwise convert: bf16 copy of x ---------------------------------------------
__global__ __launch_bounds__(256) void k_xconv(const float* __restrict__ xf,
                                               unsigned short* __restrict__ xb)
{
  const long i = ((long)blockIdx.x * 256 + threadIdx.x) * 4;
  floatx4 v = *(const floatx4*)(xf + i);
  short4v o;
#pragma unroll
  for (int u = 0; u < 4; u++) o[u] = (short)f2bf(v[u]);
  *(short4v*)(xb + i) = o;
}

// -------- fold: W[d][h*24+e] = sum_dh head[d][h*128+dh]*choice[e][dh]  (fp64) -------------
__global__ __launch_bounds__(128) void k_fold(const float* __restrict__ head,
                                              const float* __restrict__ choice,
                                              double* __restrict__ W)
{
  __shared__ double hrow[768];
  const int d = blockIdx.x;
  for (int i = threadIdx.x; i < 768; i += 128) hrow[i] = (double)head[(long)d * 768 + i];
  __syncthreads();
  for (int c = threadIdx.x; c < 144; c += 128){
    int h = c / 24, e = c % 24;
    double a = 0.0;
    const double* hr = hrow + h * 128;
    const float* ch = choice + e * 128;
#pragma unroll 8
    for (int k = 0; k < 128; k++) a += hr[k] * (double)ch[k];
    W[(long)d * 144 + c] = a;
  }
}

// -------- gates matmul: logits64[8192][144] = x @ W (fp64), 32-row blocks, full K ---------
// grid 256. block 256 = 16 tx (9 cols) x 16 ty (2 rows each). no atomics, deterministic.
__global__ __launch_bounds__(256, 2) void k_gates_mm(const float* __restrict__ xg,
                                                     const double* __restrict__ W,
                                                     double* __restrict__ logits64)
{
  __shared__ float  xs[32 * 32];    // [kk][row] fp32, 4 KB
  __shared__ double Ws[32 * 144];   // [kk][c]  fp64, 36 KB
  const int tid = threadIdx.x;
  const int tx = tid & 15;          // cols c = tx + 16j, j<9
  const int ty = tid >> 4;          // rows r = ty*2 + i, i<2
  const int row0 = blockIdx.x * 32;

  double acc[2][9];
#pragma unroll
  for (int i = 0; i < 2; i++)
#pragma unroll
    for (int j = 0; j < 9; j++) acc[i][j] = 0.0;

  for (int k0 = 0; k0 < 768; k0 += 32){
    {
      int rr = tid & 31;                 // row
      int kk4 = (tid >> 5) * 4;          // 0,4,...,28
      floatx4 v = *(const floatx4*)(xg + (long)(row0 + rr) * 768 + k0 + kk4);
#pragma unroll
      for (int u = 0; u < 4; u++) xs[(kk4 + u) * 32 + rr] = v[u];
    }
    for (int f = tid; f < 4608; f += 256) Ws[f] = W[(long)(k0 + f / 144) * 144 + (f % 144)];
    __syncthreads();
#pragma unroll 2
    for (int kk = 0; kk < 32; kk++){
      floatx2 xv = *(const floatx2*)&xs[kk * 32 + ty * 2];
      double x0 = (double)xv[0], x1d = (double)xv[1];
#pragma unroll
      for (int j = 0; j < 9; j++){
        double wv = Ws[kk * 144 + tx + 16 * j];
        acc[0][j] += x0 * wv;
        acc[1][j] += x1d * wv;
      }
    }
    __syncthreads();
  }
#pragma unroll
  for (int i = 0; i < 2; i++){
    double* dst = logits64 + (long)(row0 + ty * 2 + i) * 144;
#pragma unroll
    for (int j = 0; j < 9; j++) dst[tx + 16 * j] = acc[i][j];
  }
}

// -------- softmax over 24 experts per (token,head); write transposed gatesT[be][n] --------
__global__ __launch_bounds__(256) void k_softmax(const double* __restrict__ logits64,
                                                 double* __restrict__ gatesT)
{
  const int gid = blockIdx.x * 256 + threadIdx.x;   // < 49152
  const int R = gid / 6, h = gid % 6;
  const int b = R >> 10, s = R & 1023;
  const int n = s * 6 + h;
  const double* base = logits64 + (long)R * 144 + h * 24;
  double m = base[0];
  for (int e = 1; e < 24; e++) m = fmax(m, base[e]);
  double ssum = 0.0;
  for (int e = 0; e < 24; e++) ssum += exp(base[e] - m);
  double is = 1.0 / ssum;
  for (int e = 0; e < 24; e++)
    gatesT[((long)(b * 24 + e)) * 6144 + n] = exp(base[e] - m) * is;
}

// -------- top-K=1024 of 6144 per (b,e), exact fp64, jax tie semantics ---------------------
DEV int blk_reduce(int v, volatile int* sbuf, int tid){
#pragma unroll
  for (int off = 32; off > 0; off >>= 1) v += __shfl_down(v, off);
  __syncthreads();
  if ((tid & 63) == 0) sbuf[tid >> 6] = v;
  __syncthreads();
  return sbuf[0] + sbuf[1] + sbuf[2] + sbuf[3];
}

__global__ __launch_bounds__(256) void k_topk(const double* __restrict__ gatesT,
                                              int* __restrict__ Kidx, float* __restrict__ Gval,
                                              int* __restrict__ cnt, unsigned short* __restrict__ inv)
{
  __shared__ int sbuf[4];
  __shared__ int s_pos;
  const int tid = threadIdx.x;
  const int be = blockIdx.x;
  const int b = be / 24, e = be % 24;
  const double* g = gatesT + (long)be * 6144;

  unsigned long long key[24];
#pragma unroll
  for (int j = 0; j < 24; j++)
    key[j] = (unsigned long long)__double_as_longlong(g[tid + 256 * j]);

  unsigned long long lo = 0ull, hi = ~0ull;
  for (int it = 0; it < 64; ++it){
    if (hi - lo <= 1ull) break;
    unsigned long long mid = lo + ((hi - lo) >> 1);
    int c = 0;
#pragma unroll
    for (int j = 0; j < 24; j++) c += (key[j] > mid) ? 1 : 0;
    c = blk_reduce(c, sbuf, tid);
    if (c >= 1024) lo = mid; else hi = mid;
  }
  const unsigned long long T = hi;
  int cg = 0;
#pragma unroll
  for (int j = 0; j < 24; j++) cg += (key[j] > T) ? 1 : 0;
  cg = blk_reduce(cg, sbuf, tid);
  const int need = 1024 - cg;

  int lo2 = 0, hi2 = 6144;
  for (int it = 0; it < 13; ++it){
    if (hi2 - lo2 <= 1) break;
    int mid = (lo2 + hi2) >> 1;
    int c = 0;
#pragma unroll
    for (int j = 0; j < 24; j++) c += (key[j] == T && (tid + 256 * j) < mid) ? 1 : 0;
    c = blk_reduce(c, sbuf, tid);
    if (c >= need) hi2 = mid; else lo2 = mid;
  }
  const int m = hi2;

  if (tid == 0) s_pos = 0;
  __syncthreads();
#pragma unroll
  for (int j = 0; j < 24; j++){
    int n = tid + 256 * j;
    bool sel = (key[j] > T) || (key[j] == T && n < m);
    if (sel){
      int slot = atomicAdd(&s_pos, 1);
      Kidx[(long)be * 1024 + slot] = n;
      Gval[(long)be * 1024 + slot] = (float)__longlong_as_double((long long)key[j]);
      int t = b * 6144 + n;
      int p = atomicAdd(&cnt[t], 1);
      inv[(long)t * 24 + p] = (unsigned short)(e * 1024 + slot);
    }
  }
}

// -------- bf16 MFMA GEMM (BT input), 128x128 tile, BK=64; OUTF=1 -> fp32 C ----------------
template<int OUTF>
__global__ __launch_bounds__(256, 2) void k_gemm(const unsigned short* __restrict__ A,
    const unsigned short* __restrict__ BT, unsigned short* __restrict__ C,
    float* __restrict__ Cf, int M, int N, int K)
{
  __shared__ unsigned short As[128 * 64];
  __shared__ unsigned short Bs[128 * 64];
  const int tid = threadIdx.x;
  const int lane = tid & 63;
  const int w = tid >> 6;
  const int wy = w >> 1, wx = w & 1;
  const int m0 = blockIdx.x * 128;
  const int n0 = blockIdx.y * 128;

  floatx4 acc[4][4];
  {
    floatx4 z4 = {0.f, 0.f, 0.f, 0.f};
#pragma unroll
    for (int i = 0; i < 4; i++)
#pragma unroll
      for (int j = 0; j < 4; j++) acc[i][j] = z4;
  }

  const int rsub = lane >> 3;
  const int kcol = (lane & 7) * 8;

  for (int k0 = 0; k0 < K; k0 += 64){
#pragma unroll
    for (int i = 0; i < 4; i++){
      const int inst = w * 4 + i;
      const int rr = inst * 8 + rsub;
      gll16(A + (long)(m0 + rr) * K + k0 + kcol, &As[inst * 512], lane);
      gll16(BT + (long)(n0 + rr) * K + k0 + kcol, &Bs[inst * 512], lane);
    }
    __syncthreads();
#pragma unroll
    for (int ks = 0; ks < 2; ++ks){
      const int kb = ks * 32 + (lane >> 4) * 8;
      short8 af[4], bfr[4];
#pragma unroll
      for (int mi = 0; mi < 4; mi++) af[mi]  = *(const short8*)&As[(wy * 64 + mi * 16 + (lane & 15)) * 64 + kb];
#pragma unroll
      for (int ni = 0; ni < 4; ni++) bfr[ni] = *(const short8*)&Bs[(wx * 64 + ni * 16 + (lane & 15)) * 64 + kb];
#pragma unroll
      for (int mi = 0; mi < 4; mi++)
#pragma unroll
        for (int ni = 0; ni < 4; ni++)
          acc[mi][ni] = __builtin_amdgcn_mfma_f32_16x16x32_bf16(af[mi], bfr[ni], acc[mi][ni], 0, 0, 0);
    }
    __syncthreads();
  }

  const int ml = lane & 15;
  const int rq = (lane >> 4) * 4;
#pragma unroll
  for (int mi = 0; mi < 4; mi++){
    const int rowb = m0 + wy * 64 + mi * 16 + rq;
#pragma unroll
    for (int ni = 0; ni < 4; ni++){
      const int col = n0 + wx * 64 + ni * 16 + ml;
#pragma unroll
      for (int r = 0; r < 4; r++){
        float v = acc[mi][ni][r];
        if (OUTF) Cf[(long)(rowb + r) * N + col] = v;
        else      C[(long)(rowb + r) * N + col] = f2bf(v);
      }
    }
  }
}

// -------- fused per-expert FFN: Y[be][k][dh] = gate * (silu(gather(x1)@w1) @ w2), bf16 ----
// grid (16 m-tiles of 64 rows, 192 be). block 256. LDS ~57 KB -> 2 blocks/CU.
__global__ __launch_bounds__(256, 2) void k_ffn(const unsigned short* __restrict__ x1,
    const unsigned short* __restrict__ w1T, const unsigned short* __restrict__ w2T,
    const int* __restrict__ KidxAll, const float* __restrict__ GvalAll,
    unsigned short* __restrict__ Y)
{
  __shared__ unsigned short As[64 * 128];    // 16 KB [row][k]
  __shared__ unsigned short W1c[64 * 128];   // 16 KB [hcol][k]
  __shared__ unsigned short W2c[128 * 64];   // 16 KB [out][kchunk]
  __shared__ unsigned short Hc[64 * 72];     //  9 KB [row][hcol], padded +8 (bank +4/row)
  const int tid = threadIdx.x, lane = tid & 63, w = tid >> 6;
  const int mt = blockIdx.x;
  const int be = blockIdx.y;
  const int b = be / 24, e = be % 24;
  const int* idx = KidxAll + (long)be * 1024 + mt * 64;
  const float* scl = GvalAll + (long)be * 1024 + mt * 64;
  const unsigned short* A   = x1  + (long)b * 6144 * 128;
  const unsigned short* w1e = w1T + (long)e * 384 * 128;
  const unsigned short* w2e = w2T + (long)e * 128 * 384;

  // stage As: 64 gathered rows x 128 k. wave w: rows w*16..+16, 4 instrs x 4 rows.
  {
    const int r0 = w * 16;
#pragma unroll
    for (int i = 0; i < 4; i++){
      int rr = r0 + i * 4 + (lane >> 4);
      gll16(A + (long)idx[rr] * 128 + (lane & 15) * 8, &As[(r0 + i * 4) * 128], lane);
    }
  }

  floatx4 Yt[2][4];
  {
    floatx4 z4 = {0.f, 0.f, 0.f, 0.f};
#pragma unroll
    for (int i = 0; i < 2; i++)
#pragma unroll
      for (int j = 0; j < 4; j++) Yt[i][j] = z4;
  }

  for (int nc = 0; nc < 6; ++nc){
    {  // stage W1c: hcols nc*64..+64, full K=128
      const int r0 = w * 16;
#pragma unroll
      for (int i = 0; i < 4; i++){
        int rr = nc * 64 + r0 + i * 4 + (lane >> 4);
        gll16(w1e + (long)rr * 128 + (lane & 15) * 8, &W1c[(r0 + i * 4) * 128], lane);
      }
    }
    {  // stage W2c: all 128 outs, k-cols nc*64..+64; 4 instrs x 8 rows per wave
      const int r0 = w * 32;
#pragma unroll
      for (int i = 0; i < 4; i++){
        int rr = r0 + i * 8 + (lane >> 3);
        gll16(w2e + (long)rr * 384 + nc * 64 + (lane & 7) * 8, &W2c[(r0 + i * 8) * 64], lane);
      }
    }
    __syncthreads();   // staging done (and prev iter's stage2 reads done)

    // stage1: h chunk, wave w -> token rows w*16..+16 x 64 hcols
    floatx4 h4[4];
    {
      floatx4 z4 = {0.f, 0.f, 0.f, 0.f};
#pragma unroll
      for (int j = 0; j < 4; j++) h4[j] = z4;
    }
#pragma unroll
    for (int ks = 0; ks < 4; ++ks){
      short8 af = *(const short8*)&As[(w * 16 + (lane & 15)) * 128 + ks * 32 + (lane >> 4) * 8];
#pragma unroll
      for (int nf = 0; nf < 4; ++nf){
        short8 bfr = *(const short8*)&W1c[(nf * 16 + (lane & 15)) * 128 + ks * 32 + (lane >> 4) * 8];
        h4[nf] = __builtin_amdgcn_mfma_f32_16x16x32_bf16(af, bfr, h4[nf], 0, 0, 0);
      }
    }
    // silu -> Hc  (C layout: col=lane&15, row=(lane>>4)*4+r)
#pragma unroll
    for (int nf = 0; nf < 4; ++nf){
#pragma unroll
      for (int r = 0; r < 4; r++){
        float v = h4[nf][r];
        v = v / (1.f + __expf(-v));
        Hc[(w * 16 + (lane >> 4) * 4 + r) * 72 + nf * 16 + (lane & 15)] = f2bf(v);
      }
    }
    __syncthreads();   // Hc visible

    // stage2: YT[out][row] += W2c[out][k] (A) x Hc[row][k] (B); wave w -> outs w*32..+32
#pragma unroll
    for (int ks = 0; ks < 2; ++ks){
      short8 a2[2], b2[4];
#pragma unroll
      for (int mf = 0; mf < 2; ++mf)
        a2[mf] = *(const short8*)&W2c[(w * 32 + mf * 16 + (lane & 15)) * 64 + ks * 32 + (lane >> 4) * 8];
#pragma unroll
      for (int nf = 0; nf < 4; ++nf)
        b2[nf] = *(const short8*)&Hc[(nf * 16 + (lane & 15)) * 72 + ks * 32 + (lane >> 4) * 8];
#pragma unroll
      for (int mf = 0; mf < 2; ++mf)
#pragma unroll
        for (int nf = 0; nf < 4; ++nf)
          Yt[mf][nf] = __builtin_amdgcn_mfma_f32_16x16x32_bf16(a2[mf], b2[nf], Yt[mf][nf], 0, 0, 0);
    }
    __syncthreads();   // stage2 done; safe to overwrite W1c/W2c/Hc next iter
  }

  // epilogue: Yt element (out = w*32+mf*16+(lane>>4)*4+r, tokrow = nf*16+(lane&15));
  // write gate-scaled bf16 to Y[be][mt*64+tokrow][out] as 8B chunks.
#pragma unroll
  for (int nf = 0; nf < 4; ++nf){
    const int rb = nf * 16 + (lane & 15);
    const float g = scl[rb];
    unsigned short* dst = Y + ((long)be * 1024 + mt * 64 + rb) * 128 + w * 32 + (lane >> 4) * 4;
#pragma unroll
    for (int mf = 0; mf < 2; ++mf){
      short4v v;
#pragma unroll
      for (int r = 0; r < 4; r++) v[r] = (short)f2bf(Yt[mf][nf][r] * g);
      *(short4v*)(dst + mf * 16) = v;
    }
  }
}

// -------- combine: xout[t][:] = sum over picks of Y[e][slot][:] (gates pre-applied) -------
__global__ __launch_bounds__(256) void k_combine(const int* __restrict__ cnt,
    const unsigned short* __restrict__ inv, const unsigned short* __restrict__ Y,
    unsigned short* __restrict__ xout)
{
  const int t = blockIdx.x * 4 + (threadIdx.x >> 6);   // token id, < 49152
  const int lane = threadIdx.x & 63;
  const int b = t / 6144;
  const int c = cnt[t];
  float a0 = 0.f, a1 = 0.f;
  for (int p = 0; p < c; ++p){
    int code = inv[(long)t * 24 + p];
    int e = code >> 10, slot = code & 1023;
    const unsigned short* y = Y + (((long)(b * 24 + e) * 1024 + slot) << 7) + lane * 2;
    a0 += bf2f(y[0]); a1 += bf2f(y[1]);
  }
  unsigned short* o = xout + ((long)t << 7) + lane * 2;
  o[0] = f2bf(a0); o[1] = f2bf(a1);
}

// ==========================================================================================
extern "C" void kernel_launch(void* const* d_in, const int* in_sizes, int n_in,
                              void* d_out, int out_size, void* d_ws, size_t ws_size,
                              hipStream_t stream)
{
  const float* x      = (const float*)d_in[0];
  const float* choice = (const float*)d_in[1];
  const float* w1     = (const float*)d_in[2];
  const float* w2     = (const float*)d_in[3];
  const float* head   = (const float*)d_in[4];
  const float* merge  = (const float*)d_in[5];
  float* out = (float*)d_out;
  (void)in_sizes; (void)n_in; (void)out_size; (void)ws_size;

  char* p = (char*)d_ws;
  auto alloc = [&p](size_t bytes) -> void* {
    void* q = (void*)p; p += (bytes + 255) & ~(size_t)255; return q;
  };

  unsigned short* headT = (unsigned short*)alloc((size_t)768 * 768 * 2);
  unsigned short* mergeT= (unsigned short*)alloc((size_t)768 * 768 * 2);
  unsigned short* w1T   = (unsigned short*)alloc((size_t)24 * 384 * 128 * 2);
  unsigned short* w2T   = (unsigned short*)alloc((size_t)24 * 128 * 384 * 2);
  double* W64           = (double*)alloc((size_t)768 * 144 * 8);
  int* Kidx             = (int*)alloc((size_t)192 * 1024 * 4);
  float* Gval           = (float*)alloc((size_t)192 * 1024 * 4);
  int* cnt              = (int*)alloc((size_t)49152 * 4);
  unsigned short* inv   = (unsigned short*)alloc((size_t)49152 * 24 * 2);
  unsigned short* xb    = (unsigned short*)alloc((size_t)8192 * 768 * 2);   // 12.58 MB
  unsigned short* xout  = xb;            // xb dead after gemm0; xout live after ffn
  unsigned short* x1    = (unsigned short*)alloc((size_t)8192 * 768 * 2);   // 12.58 MB
  // big block (50.3 MB): Y; logits64/gatesT alias disjoint sub-ranges before ffn runs
  unsigned short* Y     = (unsigned short*)alloc((size_t)192 * 1024 * 128 * 2);
  double* logits64      = (double*)Y;                                       // 9.44 MB, [0, 9.44)
  double* gatesT        = (double*)((char*)Y + (size_t)8192 * 144 * 8);     // 9.44 MB, [9.44, 18.9)

  hipMemsetAsync(cnt, 0, (size_t)49152 * 4, stream);
  k_transpose<<<dim3(12, 12, 1), 256, 0, stream>>>(head, headT, 768, 768);
  k_transpose<<<dim3(12, 12, 1), 256, 0, stream>>>(merge, mergeT, 768, 768);
  k_transpose<<<dim3(6, 2, 24), 256, 0, stream>>>(w1, w1T, 128, 384);
  k_transpose<<<dim3(2, 6, 24), 256, 0, stream>>>(w2, w2T, 384, 128);
  k_fold<<<dim3(768), 128, 0, stream>>>(head, choice, W64);
  k_xconv<<<dim3(6144), 256, 0, stream>>>(x, xb);
  k_gemm<0><<<dim3(64, 6, 1), 256, 0, stream>>>(xb, headT, x1, nullptr, 8192, 768, 768);
  k_gates_mm<<<dim3(256), 256, 0, stream>>>(x, W64, logits64);
  k_softmax<<<dim3(192), 256, 0, stream>>>(logits64, gatesT);
  k_topk<<<dim3(192), 256, 0, stream>>>(gatesT, Kidx, Gval, cnt, inv);
  // logits64/gatesT dead; Y region free for ffn
  k_ffn<<<dim3(16, 192, 1), 256, 0, stream>>>(x1, w1T, w2T, Kidx, Gval, Y);
  k_combine<<<dim3(12288), 256, 0, stream>>>(cnt, inv, Y, xout);
  k_gemm<1><<<dim3(64, 6, 1), 256, 0, stream>>>(xout, mergeT, nullptr, out, 8192, 768, 768);
}

// Round 6
// 477.819 us; speedup vs baseline: 1.4519x; 1.2652x over previous
//
#include <hip/hip_runtime.h>
#include <stdint.h>
#include <math.h>

typedef __attribute__((ext_vector_type(8))) short short8;
typedef __attribute__((ext_vector_type(4))) short short4v;
typedef __attribute__((ext_vector_type(4))) float floatx4;

#define DEV static __device__ __forceinline__

DEV float bf2f(unsigned short u){ union { unsigned int i; float f; } c; c.i = ((unsigned int)u) << 16; return c.f; }
DEV unsigned short f2bf(float f){ union { float f; unsigned int i; } c; c.f = f; unsigned int u = c.i; u += 0x7fffu + ((u >> 16) & 1u); return (unsigned short)(u >> 16); }

#if defined(__has_builtin)
#if __has_builtin(__builtin_amdgcn_global_load_lds)
#define USE_GLL 1
#endif
#endif
#ifndef USE_GLL
#define USE_GLL 0
#endif

// async global->LDS, 16B per lane. ldsbase is wave-uniform; HW writes base + lane*16.
DEV void gll16(const unsigned short* g, unsigned short* ldsbase, int lane){
#if USE_GLL
  __builtin_amdgcn_global_load_lds((const __attribute__((address_space(1))) void*)g,
                                   (__attribute__((address_space(3))) void*)ldsbase, 16, 0, 0);
#else
  *(short8*)(ldsbase + lane * 8) = *(const short8*)g;
#endif
}

// -------- transpose + convert: out_bf16[C][R] = in_f32[R][C], batched over blockIdx.z ----
__global__ __launch_bounds__(256) void k_transpose(const float* __restrict__ in,
                                                   unsigned short* __restrict__ out,
                                                   int R, int C)
{
  __shared__ unsigned short tile[64 * 68];
  const int tid = threadIdx.x;
  const long boff = (long)blockIdx.z * (long)R * (long)C;
  in += boff; out += boff;
  const int c0 = blockIdx.x * 64, r0 = blockIdx.y * 64;
  const int rr = tid >> 4;
  const int c4 = (tid & 15) * 4;
#pragma unroll
  for (int i = 0; i < 4; i++){
    int r = rr + i * 16;
    floatx4 v = *(const floatx4*)(in + (long)(r0 + r) * C + c0 + c4);
#pragma unroll
    for (int u = 0; u < 4; u++) tile[r * 68 + c4 + u] = f2bf(v[u]);
  }
  __syncthreads();
#pragma unroll
  for (int i = 0; i < 4; i++){
    int cc = rr + i * 16;
    short4v v;
#pragma unroll
    for (int u = 0; u < 4; u++) v[u] = (short)tile[(c4 + u) * 68 + cc];
    *(short4v*)(out + (long)(c0 + cc) * R + r0 + c4) = v;
  }
}

// -------- elementwise convert: bf16 copy of x ---------------------------------------------
__global__ __launch_bounds__(256) void k_xconv(const float* __restrict__ xf,
                                               unsigned short* __restrict__ xb)
{
  const long i = ((long)blockIdx.x * 256 + threadIdx.x) * 4;
  floatx4 v = *(const floatx4*)(xf + i);
  short4v o;
#pragma unroll
  for (int u = 0; u < 4; u++) o[u] = (short)f2bf(v[u]);
  *(short4v*)(xb + i) = o;
}

// -------- fold: W[d][h*24+e] = sum_dh head[d][h*128+dh]*choice[e][dh]  (fp64) -------------
__global__ __launch_bounds__(128) void k_fold(const float* __restrict__ head,
                                              const float* __restrict__ choice,
                                              double* __restrict__ W)
{
  __shared__ double hrow[768];
  const int d = blockIdx.x;
  for (int i = threadIdx.x; i < 768; i += 128) hrow[i] = (double)head[(long)d * 768 + i];
  __syncthreads();
  for (int c = threadIdx.x; c < 144; c += 128){
    int h = c / 24, e = c % 24;
    double a = 0.0;
    const double* hr = hrow + h * 128;
    const float* ch = choice + e * 128;
#pragma unroll 8
    for (int k = 0; k < 128; k++) a += hr[k] * (double)ch[k];
    W[(long)d * 144 + c] = a;
  }
}

// -------- gates matmul partials: P[kseg][8192][144] = x(64-row tile) @ W(192-k seg), fp64 -
// grid (128, 4). block 256 = 16 tx (9 cols: c=tx+16j) x 16 ty (4 rows: r=ty*4+i).
// LDS 44KB -> 2 blocks/CU at grid 512 -> 8 waves/CU.
__global__ __launch_bounds__(256, 2) void k_gates_mm(const float* __restrict__ xg,
                                                     const double* __restrict__ W,
                                                     double* __restrict__ P)
{
  __shared__ float  xs[32 * 64];    // [kk][row] fp32, 8 KB
  __shared__ double Ws[32 * 144];   // [kk][c]  fp64, 36 KB
  const int tid = threadIdx.x;
  const int tx = tid & 15;
  const int ty = tid >> 4;
  const int row0 = blockIdx.x * 64;
  const int kseg = blockIdx.y * 192;

  double acc[4][9];
#pragma unroll
  for (int i = 0; i < 4; i++)
#pragma unroll
    for (int j = 0; j < 9; j++) acc[i][j] = 0.0;

  for (int kc = 0; kc < 192; kc += 32){
    const int k0 = kseg + kc;
    {
      int rr = tid & 63;                 // row
      int kk8 = (tid >> 6) * 8;          // 0,8,16,24
      const float* src = xg + (long)(row0 + rr) * 768 + k0 + kk8;
      floatx4 v0 = *(const floatx4*)src;
      floatx4 v1 = *(const floatx4*)(src + 4);
#pragma unroll
      for (int u = 0; u < 4; u++) xs[(kk8 + u) * 64 + rr] = v0[u];
#pragma unroll
      for (int u = 0; u < 4; u++) xs[(kk8 + 4 + u) * 64 + rr] = v1[u];
    }
    for (int f = tid; f < 4608; f += 256) Ws[f] = W[(long)(k0 + f / 144) * 144 + (f % 144)];
    __syncthreads();
#pragma unroll 2
    for (int kk = 0; kk < 32; kk++){
      floatx4 xv = *(const floatx4*)&xs[kk * 64 + ty * 4];   // one ds_read_b128
      double xd[4];
#pragma unroll
      for (int i = 0; i < 4; i++) xd[i] = (double)xv[i];
#pragma unroll
      for (int j = 0; j < 9; j++){
        double wv = Ws[kk * 144 + tx + 16 * j];
#pragma unroll
        for (int i = 0; i < 4; i++) acc[i][j] += xd[i] * wv;
      }
    }
    __syncthreads();
  }
  double* dstseg = P + (long)blockIdx.y * 8192 * 144;
#pragma unroll
  for (int i = 0; i < 4; i++){
    double* dst = dstseg + (long)(row0 + ty * 4 + i) * 144;
#pragma unroll
    for (int j = 0; j < 9; j++) dst[tx + 16 * j] = acc[i][j];
  }
}

// -------- reduce 4 k-seg partials -> logits64, deterministic ------------------------------
__global__ __launch_bounds__(256) void k_reduce(const double* __restrict__ P,
                                                double* __restrict__ L)
{
  const long gid = (long)blockIdx.x * 256 + threadIdx.x;   // < 8192*144
  const long S = (long)8192 * 144;
  L[gid] = ((P[gid] + P[S + gid]) + (P[2 * S + gid] + P[3 * S + gid]));
}

// -------- softmax over 24 experts per (token,head); write transposed gatesT[be][n] --------
__global__ __launch_bounds__(256) void k_softmax(const double* __restrict__ logits64,
                                                 double* __restrict__ gatesT)
{
  const int gid = blockIdx.x * 256 + threadIdx.x;   // < 49152
  const int R = gid / 6, h = gid % 6;
  const int b = R >> 10, s = R & 1023;
  const int n = s * 6 + h;
  const double* base = logits64 + (long)R * 144 + h * 24;
  double m = base[0];
  for (int e = 1; e < 24; e++) m = fmax(m, base[e]);
  double ssum = 0.0;
  for (int e = 0; e < 24; e++) ssum += exp(base[e] - m);
  double is = 1.0 / ssum;
  for (int e = 0; e < 24; e++)
    gatesT[((long)(b * 24 + e)) * 6144 + n] = exp(base[e] - m) * is;
}

// -------- top-K=1024 of 6144 per (b,e), exact fp64, jax tie semantics ---------------------
DEV int blk_reduce(int v, volatile int* sbuf, int tid){
#pragma unroll
  for (int off = 32; off > 0; off >>= 1) v += __shfl_down(v, off);
  __syncthreads();
  if ((tid & 63) == 0) sbuf[tid >> 6] = v;
  __syncthreads();
  return sbuf[0] + sbuf[1] + sbuf[2] + sbuf[3];
}

__global__ __launch_bounds__(256) void k_topk(const double* __restrict__ gatesT,
                                              int* __restrict__ Kidx, float* __restrict__ Gval,
                                              int* __restrict__ cnt, unsigned short* __restrict__ inv)
{
  __shared__ int sbuf[4];
  __shared__ int s_pos;
  const int tid = threadIdx.x;
  const int be = blockIdx.x;
  const int b = be / 24, e = be % 24;
  const double* g = gatesT + (long)be * 6144;

  unsigned long long key[24];
#pragma unroll
  for (int j = 0; j < 24; j++)
    key[j] = (unsigned long long)__double_as_longlong(g[tid + 256 * j]);

  unsigned long long lo = 0ull, hi = ~0ull;
  for (int it = 0; it < 64; ++it){
    if (hi - lo <= 1ull) break;
    unsigned long long mid = lo + ((hi - lo) >> 1);
    int c = 0;
#pragma unroll
    for (int j = 0; j < 24; j++) c += (key[j] > mid) ? 1 : 0;
    c = blk_reduce(c, sbuf, tid);
    if (c >= 1024) lo = mid; else hi = mid;
  }
  const unsigned long long T = hi;
  int cg = 0;
#pragma unroll
  for (int j = 0; j < 24; j++) cg += (key[j] > T) ? 1 : 0;
  cg = blk_reduce(cg, sbuf, tid);
  const int need = 1024 - cg;

  int lo2 = 0, hi2 = 6144;
  for (int it = 0; it < 13; ++it){
    if (hi2 - lo2 <= 1) break;
    int mid = (lo2 + hi2) >> 1;
    int c = 0;
#pragma unroll
    for (int j = 0; j < 24; j++) c += (key[j] == T && (tid + 256 * j) < mid) ? 1 : 0;
    c = blk_reduce(c, sbuf, tid);
    if (c >= need) hi2 = mid; else lo2 = mid;
  }
  const int m = hi2;

  if (tid == 0) s_pos = 0;
  __syncthreads();
#pragma unroll
  for (int j = 0; j < 24; j++){
    int n = tid + 256 * j;
    bool sel = (key[j] > T) || (key[j] == T && n < m);
    if (sel){
      int slot = atomicAdd(&s_pos, 1);
      Kidx[(long)be * 1024 + slot] = n;
      Gval[(long)be * 1024 + slot] = (float)__longlong_as_double((long long)key[j]);
      int t = b * 6144 + n;
      int p = atomicAdd(&cnt[t], 1);
      inv[(long)t * 24 + p] = (unsigned short)(e * 1024 + slot);
    }
  }
}

// -------- bf16 MFMA GEMM (BT input), 128x128 tile, BK=64; OUTF=1 -> fp32 C ----------------
template<int OUTF>
__global__ __launch_bounds__(256, 2) void k_gemm(const unsigned short* __restrict__ A,
    const unsigned short* __restrict__ BT, unsigned short* __restrict__ C,
    float* __restrict__ Cf, int M, int N, int K)
{
  __shared__ unsigned short As[128 * 64];
  __shared__ unsigned short Bs[128 * 64];
  const int tid = threadIdx.x;
  const int lane = tid & 63;
  const int w = tid >> 6;
  const int wy = w >> 1, wx = w & 1;
  const int m0 = blockIdx.x * 128;
  const int n0 = blockIdx.y * 128;

  floatx4 acc[4][4];
  {
    floatx4 z4 = {0.f, 0.f, 0.f, 0.f};
#pragma unroll
    for (int i = 0; i < 4; i++)
#pragma unroll
      for (int j = 0; j < 4; j++) acc[i][j] = z4;
  }

  const int rsub = lane >> 3;
  const int kcol = (lane & 7) * 8;

  for (int k0 = 0; k0 < K; k0 += 64){
#pragma unroll
    for (int i = 0; i < 4; i++){
      const int inst = w * 4 + i;
      const int rr = inst * 8 + rsub;
      gll16(A + (long)(m0 + rr) * K + k0 + kcol, &As[inst * 512], lane);
      gll16(BT + (long)(n0 + rr) * K + k0 + kcol, &Bs[inst * 512], lane);
    }
    __syncthreads();
#pragma unroll
    for (int ks = 0; ks < 2; ++ks){
      const int kb = ks * 32 + (lane >> 4) * 8;
      short8 af[4], bfr[4];
#pragma unroll
      for (int mi = 0; mi < 4; mi++) af[mi]  = *(const short8*)&As[(wy * 64 + mi * 16 + (lane & 15)) * 64 + kb];
#pragma unroll
      for (int ni = 0; ni < 4; ni++) bfr[ni] = *(const short8*)&Bs[(wx * 64 + ni * 16 + (lane & 15)) * 64 + kb];
#pragma unroll
      for (int mi = 0; mi < 4; mi++)
#pragma unroll
        for (int ni = 0; ni < 4; ni++)
          acc[mi][ni] = __builtin_amdgcn_mfma_f32_16x16x32_bf16(af[mi], bfr[ni], acc[mi][ni], 0, 0, 0);
    }
    __syncthreads();
  }

  const int ml = lane & 15;
  const int rq = (lane >> 4) * 4;
#pragma unroll
  for (int mi = 0; mi < 4; mi++){
    const int rowb = m0 + wy * 64 + mi * 16 + rq;
#pragma unroll
    for (int ni = 0; ni < 4; ni++){
      const int col = n0 + wx * 64 + ni * 16 + ml;
#pragma unroll
      for (int r = 0; r < 4; r++){
        float v = acc[mi][ni][r];
        if (OUTF) Cf[(long)(rowb + r) * N + col] = v;
        else      C[(long)(rowb + r) * N + col] = f2bf(v);
      }
    }
  }
}

// -------- fused per-expert FFN: Y[be][k][dh] = gate * (silu(gather(x1)@w1) @ w2), bf16 ----
// grid (16 m-tiles of 64 rows, 192 be). block 256. LDS ~57 KB -> 2 blocks/CU.
__global__ __launch_bounds__(256, 2) void k_ffn(const unsigned short* __restrict__ x1,
    const unsigned short* __restrict__ w1T, const unsigned short* __restrict__ w2T,
    const int* __restrict__ KidxAll, const float* __restrict__ GvalAll,
    unsigned short* __restrict__ Y)
{
  __shared__ unsigned short As[64 * 128];    // 16 KB [row][k]
  __shared__ unsigned short W1c[64 * 128];   // 16 KB [hcol][k]
  __shared__ unsigned short W2c[128 * 64];   // 16 KB [out][kchunk]
  __shared__ unsigned short Hc[64 * 72];     //  9 KB [row][hcol], padded +8 (bank +4/row)
  const int tid = threadIdx.x, lane = tid & 63, w = tid >> 6;
  const int mt = blockIdx.x;
  const int be = blockIdx.y;
  const int b = be / 24, e = be % 24;
  const int* idx = KidxAll + (long)be * 1024 + mt * 64;
  const float* scl = GvalAll + (long)be * 1024 + mt * 64;
  const unsigned short* A   = x1  + (long)b * 6144 * 128;
  const unsigned short* w1e = w1T + (long)e * 384 * 128;
  const unsigned short* w2e = w2T + (long)e * 128 * 384;

  {
    const int r0 = w * 16;
#pragma unroll
    for (int i = 0; i < 4; i++){
      int rr = r0 + i * 4 + (lane >> 4);
      gll16(A + (long)idx[rr] * 128 + (lane & 15) * 8, &As[(r0 + i * 4) * 128], lane);
    }
  }

  floatx4 Yt[2][4];
  {
    floatx4 z4 = {0.f, 0.f, 0.f, 0.f};
#pragma unroll
    for (int i = 0; i < 2; i++)
#pragma unroll
      for (int j = 0; j < 4; j++) Yt[i][j] = z4;
  }

  for (int nc = 0; nc < 6; ++nc){
    {
      const int r0 = w * 16;
#pragma unroll
      for (int i = 0; i < 4; i++){
        int rr = nc * 64 + r0 + i * 4 + (lane >> 4);
        gll16(w1e + (long)rr * 128 + (lane & 15) * 8, &W1c[(r0 + i * 4) * 128], lane);
      }
    }
    {
      const int r0 = w * 32;
#pragma unroll
      for (int i = 0; i < 4; i++){
        int rr = r0 + i * 8 + (lane >> 3);
        gll16(w2e + (long)rr * 384 + nc * 64 + (lane & 7) * 8, &W2c[(r0 + i * 8) * 64], lane);
      }
    }
    __syncthreads();

    floatx4 h4[4];
    {
      floatx4 z4 = {0.f, 0.f, 0.f, 0.f};
#pragma unroll
      for (int j = 0; j < 4; j++) h4[j] = z4;
    }
#pragma unroll
    for (int ks = 0; ks < 4; ++ks){
      short8 af = *(const short8*)&As[(w * 16 + (lane & 15)) * 128 + ks * 32 + (lane >> 4) * 8];
#pragma unroll
      for (int nf = 0; nf < 4; ++nf){
        short8 bfr = *(const short8*)&W1c[(nf * 16 + (lane & 15)) * 128 + ks * 32 + (lane >> 4) * 8];
        h4[nf] = __builtin_amdgcn_mfma_f32_16x16x32_bf16(af, bfr, h4[nf], 0, 0, 0);
      }
    }
#pragma unroll
    for (int nf = 0; nf < 4; ++nf){
#pragma unroll
      for (int r = 0; r < 4; r++){
        float v = h4[nf][r];
        v = v / (1.f + __expf(-v));
        Hc[(w * 16 + (lane >> 4) * 4 + r) * 72 + nf * 16 + (lane & 15)] = f2bf(v);
      }
    }
    __syncthreads();

#pragma unroll
    for (int ks = 0; ks < 2; ++ks){
      short8 a2[2], b2[4];
#pragma unroll
      for (int mf = 0; mf < 2; ++mf)
        a2[mf] = *(const short8*)&W2c[(w * 32 + mf * 16 + (lane & 15)) * 64 + ks * 32 + (lane >> 4) * 8];
#pragma unroll
      for (int nf = 0; nf < 4; ++nf)
        b2[nf] = *(const short8*)&Hc[(nf * 16 + (lane & 15)) * 72 + ks * 32 + (lane >> 4) * 8];
#pragma unroll
      for (int mf = 0; mf < 2; ++mf)
#pragma unroll
        for (int nf = 0; nf < 4; ++nf)
          Yt[mf][nf] = __builtin_amdgcn_mfma_f32_16x16x32_bf16(a2[mf], b2[nf], Yt[mf][nf], 0, 0, 0);
    }
    __syncthreads();
  }

#pragma unroll
  for (int nf = 0; nf < 4; ++nf){
    const int rb = nf * 16 + (lane & 15);
    const float g = scl[rb];
    unsigned short* dst = Y + ((long)be * 1024 + mt * 64 + rb) * 128 + w * 32 + (lane >> 4) * 4;
#pragma unroll
    for (int mf = 0; mf < 2; ++mf){
      short4v v;
#pragma unroll
      for (int r = 0; r < 4; r++) v[r] = (short)f2bf(Yt[mf][nf][r] * g);
      *(short4v*)(dst + mf * 16) = v;
    }
  }
}

// -------- combine: xout[t][:] = sum over picks of Y[e][slot][:] (gates pre-applied) -------
__global__ __launch_bounds__(256) void k_combine(const int* __restrict__ cnt,
    const unsigned short* __restrict__ inv, const unsigned short* __restrict__ Y,
    unsigned short* __restrict__ xout)
{
  const int t = blockIdx.x * 4 + (threadIdx.x >> 6);   // token id, < 49152
  const int lane = threadIdx.x & 63;
  const int b = t / 6144;
  const int c = cnt[t];
  float a0 = 0.f, a1 = 0.f;
  for (int p = 0; p < c; ++p){
    int code = inv[(long)t * 24 + p];
    int e = code >> 10, slot = code & 1023;
    const unsigned short* y = Y + (((long)(b * 24 + e) * 1024 + slot) << 7) + lane * 2;
    a0 += bf2f(y[0]); a1 += bf2f(y[1]);
  }
  unsigned short* o = xout + ((long)t << 7) + lane * 2;
  o[0] = f2bf(a0); o[1] = f2bf(a1);
}

// ==========================================================================================
extern "C" void kernel_launch(void* const* d_in, const int* in_sizes, int n_in,
                              void* d_out, int out_size, void* d_ws, size_t ws_size,
                              hipStream_t stream)
{
  const float* x      = (const float*)d_in[0];
  const float* choice = (const float*)d_in[1];
  const float* w1     = (const float*)d_in[2];
  const float* w2     = (const float*)d_in[3];
  const float* head   = (const float*)d_in[4];
  const float* merge  = (const float*)d_in[5];
  float* out = (float*)d_out;
  (void)in_sizes; (void)n_in; (void)out_size; (void)ws_size;

  char* p = (char*)d_ws;
  auto alloc = [&p](size_t bytes) -> void* {
    void* q = (void*)p; p += (bytes + 255) & ~(size_t)255; return q;
  };

  unsigned short* headT = (unsigned short*)alloc((size_t)768 * 768 * 2);
  unsigned short* mergeT= (unsigned short*)alloc((size_t)768 * 768 * 2);
  unsigned short* w1T   = (unsigned short*)alloc((size_t)24 * 384 * 128 * 2);
  unsigned short* w2T   = (unsigned short*)alloc((size_t)24 * 128 * 384 * 2);
  double* W64           = (double*)alloc((size_t)768 * 144 * 8);
  int* Kidx             = (int*)alloc((size_t)192 * 1024 * 4);
  float* Gval           = (float*)alloc((size_t)192 * 1024 * 4);
  int* cnt              = (int*)alloc((size_t)49152 * 4);
  unsigned short* inv   = (unsigned short*)alloc((size_t)49152 * 24 * 2);
  unsigned short* xb    = (unsigned short*)alloc((size_t)8192 * 768 * 2);   // 12.58 MB
  unsigned short* x1    = (unsigned short*)alloc((size_t)8192 * 768 * 2);   // 12.58 MB
  // big region (50.33 MB): Y for ffn; before topk it hosts P (37.75) + gatesT (9.44)
  unsigned short* Y     = (unsigned short*)alloc((size_t)192 * 1024 * 128 * 2);
  double* P             = (double*)Y;                                             // [4][8192][144]
  double* gatesT        = (double*)((char*)Y + (size_t)4 * 8192 * 144 * 8);       // 9.44 MB
  double* logits64      = (double*)xb;   // xb dead after gemm0; logits dead before combine
  unsigned short* xout  = xb;            // written by combine after logits dead

  hipMemsetAsync(cnt, 0, (size_t)49152 * 4, stream);
  k_transpose<<<dim3(12, 12, 1), 256, 0, stream>>>(head, headT, 768, 768);
  k_transpose<<<dim3(12, 12, 1), 256, 0, stream>>>(merge, mergeT, 768, 768);
  k_transpose<<<dim3(6, 2, 24), 256, 0, stream>>>(w1, w1T, 128, 384);
  k_transpose<<<dim3(2, 6, 24), 256, 0, stream>>>(w2, w2T, 384, 128);
  k_fold<<<dim3(768), 128, 0, stream>>>(head, choice, W64);
  k_xconv<<<dim3(6144), 256, 0, stream>>>(x, xb);
  k_gemm<0><<<dim3(64, 6, 1), 256, 0, stream>>>(xb, headT, x1, nullptr, 8192, 768, 768);
  // xb dead -> logits64 region usable
  k_gates_mm<<<dim3(128, 4, 1), 256, 0, stream>>>(x, W64, P);
  k_reduce<<<dim3(4608), 256, 0, stream>>>(P, logits64);
  k_softmax<<<dim3(192), 256, 0, stream>>>(logits64, gatesT);
  k_topk<<<dim3(192), 256, 0, stream>>>(gatesT, Kidx, Gval, cnt, inv);
  // P/gatesT dead; Y region free for ffn
  k_ffn<<<dim3(16, 192, 1), 256, 0, stream>>>(x1, w1T, w2T, Kidx, Gval, Y);
  k_combine<<<dim3(12288), 256, 0, stream>>>(cnt, inv, Y, xout);
  k_gemm<1><<<dim3(64, 6, 1), 256, 0, stream>>>(xout, mergeT, nullptr, out, 8192, 768, 768);
}

// Round 7
// 427.276 us; speedup vs baseline: 1.6236x; 1.1183x over previous
//
#include <hip/hip_runtime.h>
#include <stdint.h>
#include <math.h>

typedef __attribute__((ext_vector_type(8))) short short8;
typedef __attribute__((ext_vector_type(4))) short short4v;
typedef __attribute__((ext_vector_type(4))) float floatx4;

#define DEV static __device__ __forceinline__

DEV float bf2f(unsigned short u){ union { unsigned int i; float f; } c; c.i = ((unsigned int)u) << 16; return c.f; }
DEV unsigned short f2bf(float f){ union { float f; unsigned int i; } c; c.f = f; unsigned int u = c.i; u += 0x7fffu + ((u >> 16) & 1u); return (unsigned short)(u >> 16); }

#if defined(__has_builtin)
#if __has_builtin(__builtin_amdgcn_global_load_lds)
#define USE_GLL 1
#endif
#endif
#ifndef USE_GLL
#define USE_GLL 0
#endif

// async global->LDS, 16B per lane. ldsbase is wave-uniform; HW writes base + lane*16.
DEV void gll16(const unsigned short* g, unsigned short* ldsbase, int lane){
#if USE_GLL
  __builtin_amdgcn_global_load_lds((const __attribute__((address_space(1))) void*)g,
                                   (__attribute__((address_space(3))) void*)ldsbase, 16, 0, 0);
#else
  *(short8*)(ldsbase + lane * 8) = *(const short8*)g;
#endif
}

// -------- transpose + convert: out_bf16[C][R] = in_f32[R][C], batched over blockIdx.z ----
__global__ __launch_bounds__(256) void k_transpose(const float* __restrict__ in,
                                                   unsigned short* __restrict__ out,
                                                   int R, int C)
{
  __shared__ unsigned short tile[64 * 68];
  const int tid = threadIdx.x;
  const long boff = (long)blockIdx.z * (long)R * (long)C;
  in += boff; out += boff;
  const int c0 = blockIdx.x * 64, r0 = blockIdx.y * 64;
  const int rr = tid >> 4;
  const int c4 = (tid & 15) * 4;
#pragma unroll
  for (int i = 0; i < 4; i++){
    int r = rr + i * 16;
    floatx4 v = *(const floatx4*)(in + (long)(r0 + r) * C + c0 + c4);
#pragma unroll
    for (int u = 0; u < 4; u++) tile[r * 68 + c4 + u] = f2bf(v[u]);
  }
  __syncthreads();
#pragma unroll
  for (int i = 0; i < 4; i++){
    int cc = rr + i * 16;
    short4v v;
#pragma unroll
    for (int u = 0; u < 4; u++) v[u] = (short)tile[(c4 + u) * 68 + cc];
    *(short4v*)(out + (long)(c0 + cc) * R + r0 + c4) = v;
  }
}

// -------- elementwise convert: bf16 copy of x ---------------------------------------------
__global__ __launch_bounds__(256) void k_xconv(const float* __restrict__ xf,
                                               unsigned short* __restrict__ xb)
{
  const long i = ((long)blockIdx.x * 256 + threadIdx.x) * 4;
  floatx4 v = *(const floatx4*)(xf + i);
  short4v o;
#pragma unroll
  for (int u = 0; u < 4; u++) o[u] = (short)f2bf(v[u]);
  *(short4v*)(xb + i) = o;
}

// -------- fold: W[d][h*24+e] = sum_dh head[d][h*128+dh]*choice[e][dh]  (fp64) -------------
__global__ __launch_bounds__(128) void k_fold(const float* __restrict__ head,
                                              const float* __restrict__ choice,
                                              double* __restrict__ W)
{
  __shared__ double hrow[768];
  const int d = blockIdx.x;
  for (int i = threadIdx.x; i < 768; i += 128) hrow[i] = (double)head[(long)d * 768 + i];
  __syncthreads();
  for (int c = threadIdx.x; c < 144; c += 128){
    int h = c / 24, e = c % 24;
    double a = 0.0;
    const double* hr = hrow + h * 128;
    const float* ch = choice + e * 128;
#pragma unroll 8
    for (int k = 0; k < 128; k++) a += hr[k] * (double)ch[k];
    W[(long)d * 144 + c] = a;
  }
}

// -------- gates matmul partials: P[kseg][8192][144] = x(64-row tile) @ W(192-k seg), fp64 -
__global__ __launch_bounds__(256, 2) void k_gates_mm(const float* __restrict__ xg,
                                                     const double* __restrict__ W,
                                                     double* __restrict__ P)
{
  __shared__ float  xs[32 * 64];    // [kk][row] fp32, 8 KB
  __shared__ double Ws[32 * 144];   // [kk][c]  fp64, 36 KB
  const int tid = threadIdx.x;
  const int tx = tid & 15;
  const int ty = tid >> 4;
  const int row0 = blockIdx.x * 64;
  const int kseg = blockIdx.y * 192;

  double acc[4][9];
#pragma unroll
  for (int i = 0; i < 4; i++)
#pragma unroll
    for (int j = 0; j < 9; j++) acc[i][j] = 0.0;

  for (int kc = 0; kc < 192; kc += 32){
    const int k0 = kseg + kc;
    {
      int rr = tid & 63;                 // row
      int kk8 = (tid >> 6) * 8;          // 0,8,16,24
      const float* src = xg + (long)(row0 + rr) * 768 + k0 + kk8;
      floatx4 v0 = *(const floatx4*)src;
      floatx4 v1 = *(const floatx4*)(src + 4);
#pragma unroll
      for (int u = 0; u < 4; u++) xs[(kk8 + u) * 64 + rr] = v0[u];
#pragma unroll
      for (int u = 0; u < 4; u++) xs[(kk8 + 4 + u) * 64 + rr] = v1[u];
    }
    for (int f = tid; f < 4608; f += 256) Ws[f] = W[(long)(k0 + f / 144) * 144 + (f % 144)];
    __syncthreads();
#pragma unroll 2
    for (int kk = 0; kk < 32; kk++){
      floatx4 xv = *(const floatx4*)&xs[kk * 64 + ty * 4];   // one ds_read_b128
      double xd[4];
#pragma unroll
      for (int i = 0; i < 4; i++) xd[i] = (double)xv[i];
#pragma unroll
      for (int j = 0; j < 9; j++){
        double wv = Ws[kk * 144 + tx + 16 * j];
#pragma unroll
        for (int i = 0; i < 4; i++) acc[i][j] += xd[i] * wv;
      }
    }
    __syncthreads();
  }
  double* dstseg = P + (long)blockIdx.y * 8192 * 144;
#pragma unroll
  for (int i = 0; i < 4; i++){
    double* dst = dstseg + (long)(row0 + ty * 4 + i) * 144;
#pragma unroll
    for (int j = 0; j < 9; j++) dst[tx + 16 * j] = acc[i][j];
  }
}

// -------- reduce 4 k-seg partials -> logits64, deterministic ------------------------------
__global__ __launch_bounds__(256) void k_reduce(const double* __restrict__ P,
                                                double* __restrict__ L)
{
  const long gid = (long)blockIdx.x * 256 + threadIdx.x;   // < 8192*144
  const long S = (long)8192 * 144;
  L[gid] = ((P[gid] + P[S + gid]) + (P[2 * S + gid] + P[3 * S + gid]));
}

// -------- softmax over 24 experts per (token,head); write transposed gatesT[be][n] --------
__global__ __launch_bounds__(256) void k_softmax(const double* __restrict__ logits64,
                                                 double* __restrict__ gatesT)
{
  const int gid = blockIdx.x * 256 + threadIdx.x;   // < 49152
  const int R = gid / 6, h = gid % 6;
  const int b = R >> 10, s = R & 1023;
  const int n = s * 6 + h;
  const double* base = logits64 + (long)R * 144 + h * 24;
  double m = base[0];
  for (int e = 1; e < 24; e++) m = fmax(m, base[e]);
  double ssum = 0.0;
  for (int e = 0; e < 24; e++) ssum += exp(base[e] - m);
  double is = 1.0 / ssum;
  for (int e = 0; e < 24; e++)
    gatesT[((long)(b * 24 + e)) * 6144 + n] = exp(base[e] - m) * is;
}

// -------- top-K=1024 of 6144 per (b,e), exact fp64, jax tie semantics ---------------------
DEV int blk_reduce(int v, volatile int* sbuf, int tid){
#pragma unroll
  for (int off = 32; off > 0; off >>= 1) v += __shfl_down(v, off);
  __syncthreads();
  if ((tid & 63) == 0) sbuf[tid >> 6] = v;
  __syncthreads();
  return sbuf[0] + sbuf[1] + sbuf[2] + sbuf[3];
}

__global__ __launch_bounds__(256) void k_topk(const double* __restrict__ gatesT,
                                              int* __restrict__ Kidx, float* __restrict__ Gval,
                                              int* __restrict__ cnt, unsigned short* __restrict__ inv)
{
  __shared__ int sbuf[4];
  __shared__ int s_pos;
  const int tid = threadIdx.x;
  const int be = blockIdx.x;
  const int b = be / 24, e = be % 24;
  const double* g = gatesT + (long)be * 6144;

  unsigned long long key[24];
#pragma unroll
  for (int j = 0; j < 24; j++)
    key[j] = (unsigned long long)__double_as_longlong(g[tid + 256 * j]);

  unsigned long long lo = 0ull, hi = ~0ull;
  for (int it = 0; it < 64; ++it){
    if (hi - lo <= 1ull) break;
    unsigned long long mid = lo + ((hi - lo) >> 1);
    int c = 0;
#pragma unroll
    for (int j = 0; j < 24; j++) c += (key[j] > mid) ? 1 : 0;
    c = blk_reduce(c, sbuf, tid);
    if (c >= 1024) lo = mid; else hi = mid;
  }
  const unsigned long long T = hi;
  int cg = 0;
#pragma unroll
  for (int j = 0; j < 24; j++) cg += (key[j] > T) ? 1 : 0;
  cg = blk_reduce(cg, sbuf, tid);
  const int need = 1024 - cg;

  int lo2 = 0, hi2 = 6144;
  for (int it = 0; it < 13; ++it){
    if (hi2 - lo2 <= 1) break;
    int mid = (lo2 + hi2) >> 1;
    int c = 0;
#pragma unroll
    for (int j = 0; j < 24; j++) c += (key[j] == T && (tid + 256 * j) < mid) ? 1 : 0;
    c = blk_reduce(c, sbuf, tid);
    if (c >= need) hi2 = mid; else lo2 = mid;
  }
  const int m = hi2;

  if (tid == 0) s_pos = 0;
  __syncthreads();
#pragma unroll
  for (int j = 0; j < 24; j++){
    int n = tid + 256 * j;
    bool sel = (key[j] > T) || (key[j] == T && n < m);
    if (sel){
      int slot = atomicAdd(&s_pos, 1);
      Kidx[(long)be * 1024 + slot] = n;
      Gval[(long)be * 1024 + slot] = (float)__longlong_as_double((long long)key[j]);
      int t = b * 6144 + n;
      int p = atomicAdd(&cnt[t], 1);
      inv[(long)t * 24 + p] = (unsigned short)(e * 1024 + slot);
    }
  }
}

// -------- bf16 MFMA GEMM (BT input), 128x128 tile, BK=64; OUTF=1 -> fp32 C ----------------
template<int OUTF>
__global__ __launch_bounds__(256, 2) void k_gemm(const unsigned short* __restrict__ A,
    const unsigned short* __restrict__ BT, unsigned short* __restrict__ C,
    float* __restrict__ Cf, int M, int N, int K)
{
  __shared__ unsigned short As[128 * 64];
  __shared__ unsigned short Bs[128 * 64];
  const int tid = threadIdx.x;
  const int lane = tid & 63;
  const int w = tid >> 6;
  const int wy = w >> 1, wx = w & 1;
  const int m0 = blockIdx.x * 128;
  const int n0 = blockIdx.y * 128;

  floatx4 acc[4][4];
  {
    floatx4 z4 = {0.f, 0.f, 0.f, 0.f};
#pragma unroll
    for (int i = 0; i < 4; i++)
#pragma unroll
      for (int j = 0; j < 4; j++) acc[i][j] = z4;
  }

  const int rsub = lane >> 3;
  const int kcol = (lane & 7) * 8;

  for (int k0 = 0; k0 < K; k0 += 64){
#pragma unroll
    for (int i = 0; i < 4; i++){
      const int inst = w * 4 + i;
      const int rr = inst * 8 + rsub;
      gll16(A + (long)(m0 + rr) * K + k0 + kcol, &As[inst * 512], lane);
      gll16(BT + (long)(n0 + rr) * K + k0 + kcol, &Bs[inst * 512], lane);
    }
    __syncthreads();
#pragma unroll
    for (int ks = 0; ks < 2; ++ks){
      const int kb = ks * 32 + (lane >> 4) * 8;
      short8 af[4], bfr[4];
#pragma unroll
      for (int mi = 0; mi < 4; mi++) af[mi]  = *(const short8*)&As[(wy * 64 + mi * 16 + (lane & 15)) * 64 + kb];
#pragma unroll
      for (int ni = 0; ni < 4; ni++) bfr[ni] = *(const short8*)&Bs[(wx * 64 + ni * 16 + (lane & 15)) * 64 + kb];
#pragma unroll
      for (int mi = 0; mi < 4; mi++)
#pragma unroll
        for (int ni = 0; ni < 4; ni++)
          acc[mi][ni] = __builtin_amdgcn_mfma_f32_16x16x32_bf16(af[mi], bfr[ni], acc[mi][ni], 0, 0, 0);
    }
    __syncthreads();
  }

  const int ml = lane & 15;
  const int rq = (lane >> 4) * 4;
#pragma unroll
  for (int mi = 0; mi < 4; mi++){
    const int rowb = m0 + wy * 64 + mi * 16 + rq;
#pragma unroll
    for (int ni = 0; ni < 4; ni++){
      const int col = n0 + wx * 64 + ni * 16 + ml;
#pragma unroll
      for (int r = 0; r < 4; r++){
        float v = acc[mi][ni][r];
        if (OUTF) Cf[(long)(rowb + r) * N + col] = v;
        else      C[(long)(rowb + r) * N + col] = f2bf(v);
      }
    }
  }
}

// -------- fused per-expert FFN: Y[be][k][dh] = gate * (silu(gather(x1)@w1) @ w2), bf16 ----
// grid (16 m-tiles of 64 rows, 192 be). block 256. LDS ~57 KB -> 2 blocks/CU.
// LDS chunk-XOR swizzle (row-major 16B chunks): slot p of row r holds global chunk p^(r&15)
// (As/W1c, 16 chunks/row) or p^(r&7) (W2c, 8 chunks/row) -> fragment reads go from ~16-way
// bank conflicts (row stride = 0 mod 32 banks) to <=2-way (free, m136).
__global__ __launch_bounds__(256, 2) void k_ffn(const unsigned short* __restrict__ x1,
    const unsigned short* __restrict__ w1T, const unsigned short* __restrict__ w2T,
    const int* __restrict__ KidxAll, const float* __restrict__ GvalAll,
    unsigned short* __restrict__ Y)
{
  __shared__ unsigned short As[64 * 128];    // 16 KB [row][k], swizzled
  __shared__ unsigned short W1c[64 * 128];   // 16 KB [hcol][k], swizzled
  __shared__ unsigned short W2c[128 * 64];   // 16 KB [out][kchunk], swizzled
  __shared__ unsigned short Hc[64 * 72];     //  9 KB [row][hcol], padded +8
  const int tid = threadIdx.x, lane = tid & 63, w = tid >> 6;
  const int mt = blockIdx.x;
  const int be = blockIdx.y;
  const int b = be / 24, e = be % 24;
  const int* idx = KidxAll + (long)be * 1024 + mt * 64;
  const float* scl = GvalAll + (long)be * 1024 + mt * 64;
  const unsigned short* A   = x1  + (long)b * 6144 * 128;
  const unsigned short* w1e = w1T + (long)e * 384 * 128;
  const unsigned short* w2e = w2T + (long)e * 128 * 384;

  // stage As: 64 gathered rows x 128 k. lane ℓ of instr i -> row r0+i*4+(ℓ>>4), slot ℓ&15,
  // source chunk (ℓ&15)^(row&15).
  {
    const int r0 = w * 16;
#pragma unroll
    for (int i = 0; i < 4; i++){
      int rr = r0 + i * 4 + (lane >> 4);
      int c = (lane & 15) ^ (rr & 15);
      gll16(A + (long)idx[rr] * 128 + c * 8, &As[(r0 + i * 4) * 128], lane);
    }
  }

  floatx4 Yt[2][4];
  {
    floatx4 z4 = {0.f, 0.f, 0.f, 0.f};
#pragma unroll
    for (int i = 0; i < 2; i++)
#pragma unroll
      for (int j = 0; j < 4; j++) Yt[i][j] = z4;
  }

  for (int nc = 0; nc < 6; ++nc){
    {  // stage W1c: hcols nc*64..+64, full K=128 (swizzled like As)
      const int r0 = w * 16;
#pragma unroll
      for (int i = 0; i < 4; i++){
        int lr = r0 + i * 4 + (lane >> 4);         // local hcol 0..63
        int c = (lane & 15) ^ (lr & 15);
        gll16(w1e + (long)(nc * 64 + lr) * 128 + c * 8, &W1c[(r0 + i * 4) * 128], lane);
      }
    }
    {  // stage W2c: 128 outs x 64 k (8 chunks/row, swizzle ^(row&7))
      const int r0 = w * 32;
#pragma unroll
      for (int i = 0; i < 4; i++){
        int rr = r0 + i * 8 + (lane >> 3);
        int c = (lane & 7) ^ (rr & 7);
        gll16(w2e + (long)rr * 384 + nc * 64 + c * 8, &W2c[(r0 + i * 8) * 64], lane);
      }
    }
    __syncthreads();   // staging done (and prev iter's stage2 reads done)

    // stage1: h chunk, wave w -> token rows w*16..+16 x 64 hcols
    floatx4 h4[4];
    {
      floatx4 z4 = {0.f, 0.f, 0.f, 0.f};
#pragma unroll
      for (int j = 0; j < 4; j++) h4[j] = z4;
    }
#pragma unroll
    for (int ks = 0; ks < 4; ++ks){
      const int chunk = ks * 4 + (lane >> 4);               // 0..15
      const int pos = chunk ^ (lane & 15);                  // row&15 == lane&15
      short8 af = *(const short8*)&As[(w * 16 + (lane & 15)) * 128 + pos * 8];
#pragma unroll
      for (int nf = 0; nf < 4; ++nf){
        short8 bfr = *(const short8*)&W1c[(nf * 16 + (lane & 15)) * 128 + pos * 8];
        h4[nf] = __builtin_amdgcn_mfma_f32_16x16x32_bf16(af, bfr, h4[nf], 0, 0, 0);
      }
    }
    // silu -> Hc  (C layout: col=lane&15, row=(lane>>4)*4+r)
#pragma unroll
    for (int nf = 0; nf < 4; ++nf){
#pragma unroll
      for (int r = 0; r < 4; r++){
        float v = h4[nf][r];
        v = v / (1.f + __expf(-v));
        Hc[(w * 16 + (lane >> 4) * 4 + r) * 72 + nf * 16 + (lane & 15)] = f2bf(v);
      }
    }
    __syncthreads();   // Hc visible

    // stage2: YT[out][row] += W2c[out][k] (A) x Hc[row][k] (B); wave w -> outs w*32..+32
#pragma unroll
    for (int ks = 0; ks < 2; ++ks){
      const int chunk2 = ks * 4 + (lane >> 4);              // 0..7
      short8 a2[2], b2[4];
#pragma unroll
      for (int mf = 0; mf < 2; ++mf){
        const int row2 = w * 32 + mf * 16 + (lane & 15);
        const int pos2 = chunk2 ^ (row2 & 7);
        a2[mf] = *(const short8*)&W2c[row2 * 64 + pos2 * 8];
      }
#pragma unroll
      for (int nf = 0; nf < 4; ++nf)
        b2[nf] = *(const short8*)&Hc[(nf * 16 + (lane & 15)) * 72 + ks * 32 + (lane >> 4) * 8];
#pragma unroll
      for (int mf = 0; mf < 2; ++mf)
#pragma unroll
        for (int nf = 0; nf < 4; ++nf)
          Yt[mf][nf] = __builtin_amdgcn_mfma_f32_16x16x32_bf16(a2[mf], b2[nf], Yt[mf][nf], 0, 0, 0);
    }
    __syncthreads();   // stage2 done; safe to overwrite W1c/W2c/Hc next iter
  }

  // epilogue: Yt element (out = w*32+mf*16+(lane>>4)*4+r, tokrow = nf*16+(lane&15));
#pragma unroll
  for (int nf = 0; nf < 4; ++nf){
    const int rb = nf * 16 + (lane & 15);
    const float g = scl[rb];
    unsigned short* dst = Y + ((long)be * 1024 + mt * 64 + rb) * 128 + w * 32 + (lane >> 4) * 4;
#pragma unroll
    for (int mf = 0; mf < 2; ++mf){
      short4v v;
#pragma unroll
      for (int r = 0; r < 4; r++) v[r] = (short)f2bf(Yt[mf][nf][r] * g);
      *(short4v*)(dst + mf * 16) = v;
    }
  }
}

// -------- combine: xout[t][:] = sum over picks of Y[e][slot][:] (gates pre-applied) -------
__global__ __launch_bounds__(256) void k_combine(const int* __restrict__ cnt,
    const unsigned short* __restrict__ inv, const unsigned short* __restrict__ Y,
    unsigned short* __restrict__ xout)
{
  const int t = blockIdx.x * 4 + (threadIdx.x >> 6);   // token id, < 49152
  const int lane = threadIdx.x & 63;
  const int b = t / 6144;
  const int c = cnt[t];
  float a0 = 0.f, a1 = 0.f;
  for (int p = 0; p < c; ++p){
    int code = inv[(long)t * 24 + p];
    int e = code >> 10, slot = code & 1023;
    const unsigned short* y = Y + (((long)(b * 24 + e) * 1024 + slot) << 7) + lane * 2;
    a0 += bf2f(y[0]); a1 += bf2f(y[1]);
  }
  unsigned short* o = xout + ((long)t << 7) + lane * 2;
  o[0] = f2bf(a0); o[1] = f2bf(a1);
}

// ==========================================================================================
extern "C" void kernel_launch(void* const* d_in, const int* in_sizes, int n_in,
                              void* d_out, int out_size, void* d_ws, size_t ws_size,
                              hipStream_t stream)
{
  const float* x      = (const float*)d_in[0];
  const float* choice = (const float*)d_in[1];
  const float* w1     = (const float*)d_in[2];
  const float* w2     = (const float*)d_in[3];
  const float* head   = (const float*)d_in[4];
  const float* merge  = (const float*)d_in[5];
  float* out = (float*)d_out;
  (void)in_sizes; (void)n_in; (void)out_size; (void)ws_size;

  char* p = (char*)d_ws;
  auto alloc = [&p](size_t bytes) -> void* {
    void* q = (void*)p; p += (bytes + 255) & ~(size_t)255; return q;
  };

  unsigned short* headT = (unsigned short*)alloc((size_t)768 * 768 * 2);
  unsigned short* mergeT= (unsigned short*)alloc((size_t)768 * 768 * 2);
  unsigned short* w1T   = (unsigned short*)alloc((size_t)24 * 384 * 128 * 2);
  unsigned short* w2T   = (unsigned short*)alloc((size_t)24 * 128 * 384 * 2);
  double* W64           = (double*)alloc((size_t)768 * 144 * 8);
  int* Kidx             = (int*)alloc((size_t)192 * 1024 * 4);
  float* Gval           = (float*)alloc((size_t)192 * 1024 * 4);
  int* cnt              = (int*)alloc((size_t)49152 * 4);
  unsigned short* inv   = (unsigned short*)alloc((size_t)49152 * 24 * 2);
  unsigned short* xb    = (unsigned short*)alloc((size_t)8192 * 768 * 2);   // 12.58 MB
  unsigned short* x1    = (unsigned short*)alloc((size_t)8192 * 768 * 2);   // 12.58 MB
  // big region (50.33 MB): Y for ffn; before topk it hosts P (37.75) + gatesT (9.44)
  unsigned short* Y     = (unsigned short*)alloc((size_t)192 * 1024 * 128 * 2);
  double* P             = (double*)Y;                                             // [4][8192][144]
  double* gatesT        = (double*)((char*)Y + (size_t)4 * 8192 * 144 * 8);       // 9.44 MB
  double* logits64      = (double*)xb;   // xb dead after gemm0; logits dead before combine
  unsigned short* xout  = xb;            // written by combine after logits dead

  hipMemsetAsync(cnt, 0, (size_t)49152 * 4, stream);
  k_transpose<<<dim3(12, 12, 1), 256, 0, stream>>>(head, headT, 768, 768);
  k_transpose<<<dim3(12, 12, 1), 256, 0, stream>>>(merge, mergeT, 768, 768);
  k_transpose<<<dim3(6, 2, 24), 256, 0, stream>>>(w1, w1T, 128, 384);
  k_transpose<<<dim3(2, 6, 24), 256, 0, stream>>>(w2, w2T, 384, 128);
  k_fold<<<dim3(768), 128, 0, stream>>>(head, choice, W64);
  k_xconv<<<dim3(6144), 256, 0, stream>>>(x, xb);
  k_gemm<0><<<dim3(64, 6, 1), 256, 0, stream>>>(xb, headT, x1, nullptr, 8192, 768, 768);
  // xb dead -> logits64 region usable
  k_gates_mm<<<dim3(128, 4, 1), 256, 0, stream>>>(x, W64, P);
  k_reduce<<<dim3(4608), 256, 0, stream>>>(P, logits64);
  k_softmax<<<dim3(192), 256, 0, stream>>>(logits64, gatesT);
  k_topk<<<dim3(192), 256, 0, stream>>>(gatesT, Kidx, Gval, cnt, inv);
  // P/gatesT dead; Y region free for ffn
  k_ffn<<<dim3(16, 192, 1), 256, 0, stream>>>(x1, w1T, w2T, Kidx, Gval, Y);
  k_combine<<<dim3(12288), 256, 0, stream>>>(cnt, inv, Y, xout);
  k_gemm<1><<<dim3(64, 6, 1), 256, 0, stream>>>(xout, mergeT, nullptr, out, 8192, 768, 768);
}

// Round 9
// 411.463 us; speedup vs baseline: 1.6860x; 1.0384x over previous
//
#include <hip/hip_runtime.h>
#include <stdint.h>
#include <math.h>

typedef __attribute__((ext_vector_type(8))) short short8;
typedef __attribute__((ext_vector_type(4))) short short4v;
typedef __attribute__((ext_vector_type(4))) float floatx4;

#define DEV static __device__ __forceinline__

DEV float bf2f(unsigned short u){ union { unsigned int i; float f; } c; c.i = ((unsigned int)u) << 16; return c.f; }
DEV unsigned short f2bf(float f){ union { float f; unsigned int i; } c; c.f = f; unsigned int u = c.i; u += 0x7fffu + ((u >> 16) & 1u); return (unsigned short)(u >> 16); }

#if defined(__has_builtin)
#if __has_builtin(__builtin_amdgcn_global_load_lds)
#define USE_GLL 1
#endif
#endif
#ifndef USE_GLL
#define USE_GLL 0
#endif

// async global->LDS, 16B per lane. ldsbase is wave-uniform; HW writes base + lane*16.
DEV void gll16(const unsigned short* g, unsigned short* ldsbase, int lane){
#if USE_GLL
  __builtin_amdgcn_global_load_lds((const __attribute__((address_space(1))) void*)g,
                                   (__attribute__((address_space(3))) void*)ldsbase, 16, 0, 0);
#else
  *(short8*)(ldsbase + lane * 8) = *(const short8*)g;
#endif
}

// -------- transpose + convert: out_bf16[C][R] = in_f32[R][C], batched over blockIdx.z ----
__global__ __launch_bounds__(256) void k_transpose(const float* __restrict__ in,
                                                   unsigned short* __restrict__ out,
                                                   int R, int C)
{
  __shared__ unsigned short tile[64 * 68];
  const int tid = threadIdx.x;
  const long boff = (long)blockIdx.z * (long)R * (long)C;
  in += boff; out += boff;
  const int c0 = blockIdx.x * 64, r0 = blockIdx.y * 64;
  const int rr = tid >> 4;
  const int c4 = (tid & 15) * 4;
#pragma unroll
  for (int i = 0; i < 4; i++){
    int r = rr + i * 16;
    floatx4 v = *(const floatx4*)(in + (long)(r0 + r) * C + c0 + c4);
#pragma unroll
    for (int u = 0; u < 4; u++) tile[r * 68 + c4 + u] = f2bf(v[u]);
  }
  __syncthreads();
#pragma unroll
  for (int i = 0; i < 4; i++){
    int cc = rr + i * 16;
    short4v v;
#pragma unroll
    for (int u = 0; u < 4; u++) v[u] = (short)tile[(c4 + u) * 68 + cc];
    *(short4v*)(out + (long)(c0 + cc) * R + r0 + c4) = v;
  }
}

// -------- elementwise convert: bf16 copy of x ---------------------------------------------
__global__ __launch_bounds__(256) void k_xconv(const float* __restrict__ xf,
                                               unsigned short* __restrict__ xb)
{
  const long i = ((long)blockIdx.x * 256 + threadIdx.x) * 4;
  floatx4 v = *(const floatx4*)(xf + i);
  short4v o;
#pragma unroll
  for (int u = 0; u < 4; u++) o[u] = (short)f2bf(v[u]);
  *(short4v*)(xb + i) = o;
}

// -------- fold: W[d][h*24+e] = sum_dh head[d][h*128+dh]*choice[e][dh]  (fp64) -------------
__global__ __launch_bounds__(128) void k_fold(const float* __restrict__ head,
                                              const float* __restrict__ choice,
                                              double* __restrict__ W)
{
  __shared__ double hrow[768];
  const int d = blockIdx.x;
  for (int i = threadIdx.x; i < 768; i += 128) hrow[i] = (double)head[(long)d * 768 + i];
  __syncthreads();
  for (int c = threadIdx.x; c < 144; c += 128){
    int h = c / 24, e = c % 24;
    double a = 0.0;
    const double* hr = hrow + h * 128;
    const float* ch = choice + e * 128;
#pragma unroll 8
    for (int k = 0; k < 128; k++) a += hr[k] * (double)ch[k];
    W[(long)d * 144 + c] = a;
  }
}

// -------- gates matmul partials: P[kseg][8192][144] = x(64-row tile) @ W(192-k seg), fp64 -
// R6-proven VALU version. (fp64 MFMA attempt reverted: unverified D-layout scrambled routing.)
__global__ __launch_bounds__(256, 2) void k_gates_mm(const float* __restrict__ xg,
                                                     const double* __restrict__ W,
                                                     double* __restrict__ P)
{
  __shared__ float  xs[32 * 64];    // [kk][row] fp32, 8 KB
  __shared__ double Ws[32 * 144];   // [kk][c]  fp64, 36 KB
  const int tid = threadIdx.x;
  const int tx = tid & 15;
  const int ty = tid >> 4;
  const int row0 = blockIdx.x * 64;
  const int kseg = blockIdx.y * 192;

  double acc[4][9];
#pragma unroll
  for (int i = 0; i < 4; i++)
#pragma unroll
    for (int j = 0; j < 9; j++) acc[i][j] = 0.0;

  for (int kc = 0; kc < 192; kc += 32){
    const int k0 = kseg + kc;
    {
      int rr = tid & 63;
      int kk8 = (tid >> 6) * 8;
      const float* src = xg + (long)(row0 + rr) * 768 + k0 + kk8;
      floatx4 v0 = *(const floatx4*)src;
      floatx4 v1 = *(const floatx4*)(src + 4);
#pragma unroll
      for (int u = 0; u < 4; u++) xs[(kk8 + u) * 64 + rr] = v0[u];
#pragma unroll
      for (int u = 0; u < 4; u++) xs[(kk8 + 4 + u) * 64 + rr] = v1[u];
    }
    for (int f = tid; f < 4608; f += 256) Ws[f] = W[(long)(k0 + f / 144) * 144 + (f % 144)];
    __syncthreads();
#pragma unroll 2
    for (int kk = 0; kk < 32; kk++){
      floatx4 xv = *(const floatx4*)&xs[kk * 64 + ty * 4];
      double xd[4];
#pragma unroll
      for (int i = 0; i < 4; i++) xd[i] = (double)xv[i];
#pragma unroll
      for (int j = 0; j < 9; j++){
        double wv = Ws[kk * 144 + tx + 16 * j];
#pragma unroll
        for (int i = 0; i < 4; i++) acc[i][j] += xd[i] * wv;
      }
    }
    __syncthreads();
  }
  double* dstseg = P + (long)blockIdx.y * 8192 * 144;
#pragma unroll
  for (int i = 0; i < 4; i++){
    double* dst = dstseg + (long)(row0 + ty * 4 + i) * 144;
#pragma unroll
    for (int j = 0; j < 9; j++) dst[tx + 16 * j] = acc[i][j];
  }
}

// -------- fused reduce + softmax: logits from 4 partials, softmax, write gatesT[be][n] ----
__global__ __launch_bounds__(256) void k_softmax(const double* __restrict__ P,
                                                 double* __restrict__ gatesT)
{
  const int gid = blockIdx.x * 256 + threadIdx.x;   // < 49152
  const int R = gid / 6, h = gid % 6;
  const int b = R >> 10, s = R & 1023;
  const int n = s * 6 + h;
  const long S = (long)8192 * 144;
  const long base = (long)R * 144 + h * 24;
  double l[24];
#pragma unroll
  for (int e = 0; e < 24; e++){
    const long o = base + e;
    l[e] = (P[o] + P[S + o]) + (P[2 * S + o] + P[3 * S + o]);
  }
  double m = l[0];
#pragma unroll
  for (int e = 1; e < 24; e++) m = fmax(m, l[e]);
  double ssum = 0.0;
#pragma unroll
  for (int e = 0; e < 24; e++) ssum += exp(l[e] - m);
  double is = 1.0 / ssum;
#pragma unroll
  for (int e = 0; e < 24; e++)
    gatesT[((long)(b * 24 + e)) * 6144 + n] = exp(l[e] - m) * is;
}

// -------- top-K=1024 of 6144 per (b,e), exact fp64, jax tie semantics ---------------------
DEV int blk_reduce(int v, volatile int* sbuf, int tid){
#pragma unroll
  for (int off = 32; off > 0; off >>= 1) v += __shfl_down(v, off);
  __syncthreads();
  if ((tid & 63) == 0) sbuf[tid >> 6] = v;
  __syncthreads();
  return sbuf[0] + sbuf[1] + sbuf[2] + sbuf[3];
}

__global__ __launch_bounds__(256) void k_topk(const double* __restrict__ gatesT,
                                              int* __restrict__ Kidx, float* __restrict__ Gval,
                                              int* __restrict__ cnt, unsigned short* __restrict__ inv)
{
  __shared__ int sbuf[4];
  __shared__ int s_pos;
  const int tid = threadIdx.x;
  const int be = blockIdx.x;
  const int b = be / 24, e = be % 24;
  const double* g = gatesT + (long)be * 6144;

  unsigned long long key[24];
#pragma unroll
  for (int j = 0; j < 24; j++)
    key[j] = (unsigned long long)__double_as_longlong(g[tid + 256 * j]);

  unsigned long long lo = 0ull, hi = ~0ull;
  for (int it = 0; it < 64; ++it){
    if (hi - lo <= 1ull) break;
    unsigned long long mid = lo + ((hi - lo) >> 1);
    int c = 0;
#pragma unroll
    for (int j = 0; j < 24; j++) c += (key[j] > mid) ? 1 : 0;
    c = blk_reduce(c, sbuf, tid);
    if (c >= 1024) lo = mid; else hi = mid;
  }
  const unsigned long long T = hi;
  int cg = 0;
#pragma unroll
  for (int j = 0; j < 24; j++) cg += (key[j] > T) ? 1 : 0;
  cg = blk_reduce(cg, sbuf, tid);
  const int need = 1024 - cg;

  int lo2 = 0, hi2 = 6144;
  for (int it = 0; it < 13; ++it){
    if (hi2 - lo2 <= 1) break;
    int mid = (lo2 + hi2) >> 1;
    int c = 0;
#pragma unroll
    for (int j = 0; j < 24; j++) c += (key[j] == T && (tid + 256 * j) < mid) ? 1 : 0;
    c = blk_reduce(c, sbuf, tid);
    if (c >= need) hi2 = mid; else lo2 = mid;
  }
  const int m = hi2;

  if (tid == 0) s_pos = 0;
  __syncthreads();
#pragma unroll
  for (int j = 0; j < 24; j++){
    int n = tid + 256 * j;
    bool sel = (key[j] > T) || (key[j] == T && n < m);
    if (sel){
      int slot = atomicAdd(&s_pos, 1);
      Kidx[(long)be * 1024 + slot] = n;
      Gval[(long)be * 1024 + slot] = (float)__longlong_as_double((long long)key[j]);
      int t = b * 6144 + n;
      int p = atomicAdd(&cnt[t], 1);
      inv[(long)t * 24 + p] = (unsigned short)(e * 1024 + slot);
    }
  }
}

// -------- bf16 MFMA GEMM (BT input), 128x128 tile, BK=64; OUTF=1 -> fp32 C ----------------
template<int OUTF>
__global__ __launch_bounds__(256, 2) void k_gemm(const unsigned short* __restrict__ A,
    const unsigned short* __restrict__ BT, unsigned short* __restrict__ C,
    float* __restrict__ Cf, int M, int N, int K)
{
  __shared__ unsigned short As[128 * 64];
  __shared__ unsigned short Bs[128 * 64];
  const int tid = threadIdx.x;
  const int lane = tid & 63;
  const int w = tid >> 6;
  const int wy = w >> 1, wx = w & 1;
  const int m0 = blockIdx.x * 128;
  const int n0 = blockIdx.y * 128;

  floatx4 acc[4][4];
  {
    floatx4 z4 = {0.f, 0.f, 0.f, 0.f};
#pragma unroll
    for (int i = 0; i < 4; i++)
#pragma unroll
      for (int j = 0; j < 4; j++) acc[i][j] = z4;
  }

  const int rsub = lane >> 3;
  const int kcol = (lane & 7) * 8;

  for (int k0 = 0; k0 < K; k0 += 64){
#pragma unroll
    for (int i = 0; i < 4; i++){
      const int inst = w * 4 + i;
      const int rr = inst * 8 + rsub;
      gll16(A + (long)(m0 + rr) * K + k0 + kcol, &As[inst * 512], lane);
      gll16(BT + (long)(n0 + rr) * K + k0 + kcol, &Bs[inst * 512], lane);
    }
    __syncthreads();
#pragma unroll
    for (int ks = 0; ks < 2; ++ks){
      const int kb = ks * 32 + (lane >> 4) * 8;
      short8 af[4], bfr[4];
#pragma unroll
      for (int mi = 0; mi < 4; mi++) af[mi]  = *(const short8*)&As[(wy * 64 + mi * 16 + (lane & 15)) * 64 + kb];
#pragma unroll
      for (int ni = 0; ni < 4; ni++) bfr[ni] = *(const short8*)&Bs[(wx * 64 + ni * 16 + (lane & 15)) * 64 + kb];
#pragma unroll
      for (int mi = 0; mi < 4; mi++)
#pragma unroll
        for (int ni = 0; ni < 4; ni++)
          acc[mi][ni] = __builtin_amdgcn_mfma_f32_16x16x32_bf16(af[mi], bfr[ni], acc[mi][ni], 0, 0, 0);
    }
    __syncthreads();
  }

  const int ml = lane & 15;
  const int rq = (lane >> 4) * 4;
#pragma unroll
  for (int mi = 0; mi < 4; mi++){
    const int rowb = m0 + wy * 64 + mi * 16 + rq;
#pragma unroll
    for (int ni = 0; ni < 4; ni++){
      const int col = n0 + wx * 64 + ni * 16 + ml;
#pragma unroll
      for (int r = 0; r < 4; r++){
        float v = acc[mi][ni][r];
        if (OUTF) Cf[(long)(rowb + r) * N + col] = v;
        else      C[(long)(rowb + r) * N + col] = f2bf(v);
      }
    }
  }
}

// -------- fused per-expert FFN: Y[be][k][dh] = gate * (silu(gather(x1)@w1) @ w2), bf16 ----
// grid (8 m-tiles of 128 rows, 192 be). block 256. LDS exactly 80 KB -> 2 blocks/CU.
// 128-row tiles double MFMA per staged weight byte vs 64-row (R7): same 32KB W1c+W2c per
// nc-iter now feeds 64 wave-MFMAs instead of 24. All LDS XOR-chunk-swizzled (16B chunks):
// As/W1c pos = chunk^(row&15); W2c pos = chunk^(row&7); Hc pos = chunk^(tokrow&7).
__global__ __launch_bounds__(256, 2) void k_ffn(const unsigned short* __restrict__ x1,
    const unsigned short* __restrict__ w1T, const unsigned short* __restrict__ w2T,
    const int* __restrict__ KidxAll, const float* __restrict__ GvalAll,
    unsigned short* __restrict__ Y)
{
  __shared__ unsigned short As[128 * 128];   // 32 KB [row][k]
  __shared__ unsigned short W1c[64 * 128];   // 16 KB [hcol][k]
  __shared__ unsigned short W2c[128 * 64];   // 16 KB [out][hchunk]
  __shared__ unsigned short Hc[128 * 64];    // 16 KB [tokrow][hcol]
  const int tid = threadIdx.x, lane = tid & 63, w = tid >> 6;
  const int tx = lane & 15, quad = lane >> 4;
  const int mt = blockIdx.x;
  const int be = blockIdx.y;
  const int b = be / 24, e = be % 24;
  const int* idx = KidxAll + (long)be * 1024 + mt * 128;
  const float* scl = GvalAll + (long)be * 1024 + mt * 128;
  const unsigned short* A   = x1  + (long)b * 6144 * 128;
  const unsigned short* w1e = w1T + (long)e * 384 * 128;
  const unsigned short* w2e = w2T + (long)e * 128 * 384;

  // stage As: 128 gathered rows x 128 k. wave w: rows w*32..+32, 8 instrs x 4 rows.
  {
    const int r0 = w * 32;
#pragma unroll
    for (int i = 0; i < 8; i++){
      int rr = r0 + i * 4 + quad;
      int c = tx ^ (rr & 15);
      gll16(A + (long)idx[rr] * 128 + c * 8, &As[(r0 + i * 4) * 128], lane);
    }
  }

  floatx4 Yt[2][8];   // [mf out-tile][nf tokrow-tile]
  {
    floatx4 z4 = {0.f, 0.f, 0.f, 0.f};
#pragma unroll
    for (int i = 0; i < 2; i++)
#pragma unroll
      for (int j = 0; j < 8; j++) Yt[i][j] = z4;
  }

  for (int nc = 0; nc < 6; ++nc){
    {  // stage W1c: hcols nc*64..+64, full K=128; local hcol lr, swizzle ^(lr&15)
      const int r0 = w * 16;
#pragma unroll
      for (int i = 0; i < 4; i++){
        int lr = r0 + i * 4 + quad;
        int c = tx ^ (lr & 15);
        gll16(w1e + (long)(nc * 64 + lr) * 128 + c * 8, &W1c[(r0 + i * 4) * 128], lane);
      }
    }
    {  // stage W2c: 128 outs x 64 hcols (8 chunks/row, swizzle ^(row&7))
      const int r0 = w * 32;
#pragma unroll
      for (int i = 0; i < 4; i++){
        int rr = r0 + i * 8 + (lane >> 3);
        int c = (lane & 7) ^ (rr & 7);
        gll16(w2e + (long)rr * 384 + nc * 64 + c * 8, &W2c[(r0 + i * 8) * 64], lane);
      }
    }
    __syncthreads();   // staging done (and prev iter's stage2 reads done)

    // stage1: h = silu(As @ W1c^T); wave w -> rows w*32..+32 (2 mi) x 64 hcols (4 nf)
    floatx4 h4[2][4];
    {
      floatx4 z4 = {0.f, 0.f, 0.f, 0.f};
#pragma unroll
      for (int i = 0; i < 2; i++)
#pragma unroll
        for (int j = 0; j < 4; j++) h4[i][j] = z4;
    }
#pragma unroll
    for (int ks = 0; ks < 4; ++ks){
      const int chunk = ks * 4 + quad;              // K chunk 0..15
      const int pos = chunk ^ tx;                   // row&15 == tx for both As rows and W1c
      short8 af[2];
#pragma unroll
      for (int mi = 0; mi < 2; ++mi)
        af[mi] = *(const short8*)&As[(w * 32 + mi * 16 + tx) * 128 + pos * 8];
#pragma unroll
      for (int nf = 0; nf < 4; ++nf){
        short8 bfr = *(const short8*)&W1c[(nf * 16 + tx) * 128 + pos * 8];
#pragma unroll
        for (int mi = 0; mi < 2; ++mi)
          h4[mi][nf] = __builtin_amdgcn_mfma_f32_16x16x32_bf16(af[mi], bfr, h4[mi][nf], 0, 0, 0);
      }
    }
    // silu -> Hc. C layout: hcol = nf*16+tx, tokrow = w*32 + mi*16 + quad*4 + r.
    // Hc swizzled: chunk = hcol>>3, off = hcol&7, pos = chunk^(tokrow&7).
#pragma unroll
    for (int mi = 0; mi < 2; ++mi){
#pragma unroll
      for (int nf = 0; nf < 4; ++nf){
        const int hchunk = nf * 2 + (tx >> 3);
        const int hoff = tx & 7;
#pragma unroll
        for (int r = 0; r < 4; r++){
          float v = h4[mi][nf][r];
          v = v / (1.f + __expf(-v));
          const int trow = w * 32 + mi * 16 + quad * 4 + r;
          Hc[trow * 64 + (hchunk ^ (trow & 7)) * 8 + hoff] = f2bf(v);
        }
      }
    }
    __syncthreads();   // Hc visible

    // stage2: YT[out][tokrow] += W2c[out][hcol] x Hc[tokrow][hcol]; wave w -> outs w*32..+32
#pragma unroll
    for (int ks = 0; ks < 2; ++ks){
      const int chunk2 = ks * 4 + quad;             // hcol chunk 0..7
      const int posx = chunk2 ^ (tx & 7);           // row&7 == tx&7 for W2c rows and Hc rows
      short8 a2[2], b2[8];
#pragma unroll
      for (int mf = 0; mf < 2; ++mf)
        a2[mf] = *(const short8*)&W2c[(w * 32 + mf * 16 + tx) * 64 + posx * 8];
#pragma unroll
      for (int nf = 0; nf < 8; ++nf)
        b2[nf] = *(const short8*)&Hc[(nf * 16 + tx) * 64 + posx * 8];
#pragma unroll
      for (int mf = 0; mf < 2; ++mf)
#pragma unroll
        for (int nf = 0; nf < 8; ++nf)
          Yt[mf][nf] = __builtin_amdgcn_mfma_f32_16x16x32_bf16(a2[mf], b2[nf], Yt[mf][nf], 0, 0, 0);
    }
    __syncthreads();   // stage2 done; safe to overwrite W1c/W2c/Hc next iter
  }

  // epilogue: Yt element (out = w*32+mf*16+quad*4+r, tokrow = nf*16+tx)
#pragma unroll
  for (int nf = 0; nf < 8; ++nf){
    const int rb = nf * 16 + tx;
    const float g = scl[rb];
    unsigned short* dst = Y + ((long)be * 1024 + mt * 128 + rb) * 128 + w * 32 + quad * 4;
#pragma unroll
    for (int mf = 0; mf < 2; ++mf){
      short4v v;
#pragma unroll
      for (int r = 0; r < 4; r++) v[r] = (short)f2bf(Yt[mf][nf][r] * g);
      *(short4v*)(dst + mf * 16) = v;
    }
  }
}

// -------- combine: xout[t][:] = sum over picks of Y[e][slot][:] (gates pre-applied) -------
__global__ __launch_bounds__(256) void k_combine(const int* __restrict__ cnt,
    const unsigned short* __restrict__ inv, const unsigned short* __restrict__ Y,
    unsigned short* __restrict__ xout)
{
  const int t = blockIdx.x * 4 + (threadIdx.x >> 6);   // token id, < 49152
  const int lane = threadIdx.x & 63;
  const int b = t / 6144;
  const int c = cnt[t];
  float a0 = 0.f, a1 = 0.f;
  for (int p = 0; p < c; ++p){
    int code = inv[(long)t * 24 + p];
    int e = code >> 10, slot = code & 1023;
    const unsigned short* y = Y + (((long)(b * 24 + e) * 1024 + slot) << 7) + lane * 2;
    a0 += bf2f(y[0]); a1 += bf2f(y[1]);
  }
  unsigned short* o = xout + ((long)t << 7) + lane * 2;
  o[0] = f2bf(a0); o[1] = f2bf(a1);
}

// ==========================================================================================
extern "C" void kernel_launch(void* const* d_in, const int* in_sizes, int n_in,
                              void* d_out, int out_size, void* d_ws, size_t ws_size,
                              hipStream_t stream)
{
  const float* x      = (const float*)d_in[0];
  const float* choice = (const float*)d_in[1];
  const float* w1     = (const float*)d_in[2];
  const float* w2     = (const float*)d_in[3];
  const float* head   = (const float*)d_in[4];
  const float* merge  = (const float*)d_in[5];
  float* out = (float*)d_out;
  (void)in_sizes; (void)n_in; (void)out_size; (void)ws_size;

  char* p = (char*)d_ws;
  auto alloc = [&p](size_t bytes) -> void* {
    void* q = (void*)p; p += (bytes + 255) & ~(size_t)255; return q;
  };

  unsigned short* headT = (unsigned short*)alloc((size_t)768 * 768 * 2);
  unsigned short* mergeT= (unsigned short*)alloc((size_t)768 * 768 * 2);
  unsigned short* w1T   = (unsigned short*)alloc((size_t)24 * 384 * 128 * 2);
  unsigned short* w2T   = (unsigned short*)alloc((size_t)24 * 128 * 384 * 2);
  double* W64           = (double*)alloc((size_t)768 * 144 * 8);
  int* Kidx             = (int*)alloc((size_t)192 * 1024 * 4);
  float* Gval           = (float*)alloc((size_t)192 * 1024 * 4);
  int* cnt              = (int*)alloc((size_t)49152 * 4);
  unsigned short* inv   = (unsigned short*)alloc((size_t)49152 * 24 * 2);
  unsigned short* xb    = (unsigned short*)alloc((size_t)8192 * 768 * 2);   // 12.58 MB
  unsigned short* x1    = (unsigned short*)alloc((size_t)8192 * 768 * 2);   // 12.58 MB
  // big region (50.33 MB): Y for ffn; before topk it hosts P (37.75) + gatesT (9.44)
  unsigned short* Y     = (unsigned short*)alloc((size_t)192 * 1024 * 128 * 2);
  double* P             = (double*)Y;                                             // [4][8192][144]
  double* gatesT        = (double*)((char*)Y + (size_t)4 * 8192 * 144 * 8);       // 9.44 MB
  unsigned short* xout  = xb;            // xb dead after gemm0; xout written by combine

  hipMemsetAsync(cnt, 0, (size_t)49152 * 4, stream);
  k_transpose<<<dim3(12, 12, 1), 256, 0, stream>>>(head, headT, 768, 768);
  k_transpose<<<dim3(12, 12, 1), 256, 0, stream>>>(merge, mergeT, 768, 768);
  k_transpose<<<dim3(6, 2, 24), 256, 0, stream>>>(w1, w1T, 128, 384);
  k_transpose<<<dim3(2, 6, 24), 256, 0, stream>>>(w2, w2T, 384, 128);
  k_fold<<<dim3(768), 128, 0, stream>>>(head, choice, W64);
  k_xconv<<<dim3(6144), 256, 0, stream>>>(x, xb);
  k_gemm<0><<<dim3(64, 6, 1), 256, 0, stream>>>(xb, headT, x1, nullptr, 8192, 768, 768);
  k_gates_mm<<<dim3(128, 4, 1), 256, 0, stream>>>(x, W64, P);
  k_softmax<<<dim3(192), 256, 0, stream>>>(P, gatesT);
  k_topk<<<dim3(192), 256, 0, stream>>>(gatesT, Kidx, Gval, cnt, inv);
  // P/gatesT dead; Y region free for ffn
  k_ffn<<<dim3(8, 192, 1), 256, 0, stream>>>(x1, w1T, w2T, Kidx, Gval, Y);
  k_combine<<<dim3(12288), 256, 0, stream>>>(cnt, inv, Y, xout);
  k_gemm<1><<<dim3(64, 6, 1), 256, 0, stream>>>(xout, mergeT, nullptr, out, 8192, 768, 768);
}

// Round 10
// 390.905 us; speedup vs baseline: 1.7747x; 1.0526x over previous
//
#include <hip/hip_runtime.h>
#include <stdint.h>
#include <math.h>

typedef __attribute__((ext_vector_type(8))) short short8;
typedef __attribute__((ext_vector_type(4))) short short4v;
typedef __attribute__((ext_vector_type(4))) float floatx4;

#define DEV static __device__ __forceinline__

DEV float bf2f(unsigned short u){ union { unsigned int i; float f; } c; c.i = ((unsigned int)u) << 16; return c.f; }
DEV unsigned short f2bf(float f){ union { float f; unsigned int i; } c; c.f = f; unsigned int u = c.i; u += 0x7fffu + ((u >> 16) & 1u); return (unsigned short)(u >> 16); }

#if defined(__has_builtin)
#if __has_builtin(__builtin_amdgcn_global_load_lds)
#define USE_GLL 1
#endif
#if __has_builtin(__builtin_amdgcn_exp2f) && __has_builtin(__builtin_amdgcn_rcpf)
#define FAST_SILU 1
#endif
#endif
#ifndef USE_GLL
#define USE_GLL 0
#endif
#ifndef FAST_SILU
#define FAST_SILU 0
#endif

// async global->LDS, 16B per lane. ldsbase is wave-uniform; HW writes base + lane*16.
DEV void gll16(const unsigned short* g, unsigned short* ldsbase, int lane){
#if USE_GLL
  __builtin_amdgcn_global_load_lds((const __attribute__((address_space(1))) void*)g,
                                   (__attribute__((address_space(3))) void*)ldsbase, 16, 0, 0);
#else
  *(short8*)(ldsbase + lane * 8) = *(const short8*)g;
#endif
}

DEV float silu(float v){
#if FAST_SILU
  float ex = __builtin_amdgcn_exp2f(v * -1.44269504088896f);
  return v * __builtin_amdgcn_rcpf(1.f + ex);   // rcp err ~1ulp fp32, hidden by bf16 round
#else
  return v / (1.f + __expf(-v));
#endif
}

// -------- transpose tile helper: out_bf16[C][R] = in_f32[R][C] ----------------------------
DEV void transpose_tile(const float* in, unsigned short* out, int R, int C,
                        int bx, int by, int bz, int tid, unsigned short* tile)
{
  const long boff = (long)bz * (long)R * (long)C;
  in += boff; out += boff;
  const int c0 = bx * 64, r0 = by * 64;
  const int rr = tid >> 4;
  const int c4 = (tid & 15) * 4;
#pragma unroll
  for (int i = 0; i < 4; i++){
    int r = rr + i * 16;
    floatx4 v = *(const floatx4*)(in + (long)(r0 + r) * C + c0 + c4);
#pragma unroll
    for (int u = 0; u < 4; u++) tile[r * 68 + c4 + u] = f2bf(v[u]);
  }
  __syncthreads();
#pragma unroll
  for (int i = 0; i < 4; i++){
    int cc = rr + i * 16;
    short4v v;
#pragma unroll
    for (int u = 0; u < 4; u++) v[u] = (short)tile[(c4 + u) * 68 + cc];
    *(short4v*)(out + (long)(c0 + cc) * R + r0 + c4) = v;
  }
}

// -------- fused prep: 4 transposes + fold + xconv, flat block decode ----------------------
// [0,144) headT | [144,288) mergeT | [288,576) w1T | [576,864) w2T | [864,1248) fold |
// [1248,7392) xconv
__global__ __launch_bounds__(256) void k_prep(const float* __restrict__ x,
    const float* __restrict__ choice, const float* __restrict__ w1,
    const float* __restrict__ w2, const float* __restrict__ head,
    const float* __restrict__ merge,
    unsigned short* __restrict__ xb, unsigned short* __restrict__ headT,
    unsigned short* __restrict__ mergeT, unsigned short* __restrict__ w1T,
    unsigned short* __restrict__ w2T, double* __restrict__ W64)
{
  __shared__ double buf[1536];   // 12.3 KB: transpose tile (8.7 KB) or fold hrow (12.3 KB)
  unsigned short* tile = (unsigned short*)buf;
  const int id = blockIdx.x, tid = threadIdx.x;
  if (id < 144){
    transpose_tile(head, headT, 768, 768, id % 12, id / 12, 0, tid, tile);
  } else if (id < 288){
    int l = id - 144;
    transpose_tile(merge, mergeT, 768, 768, l % 12, l / 12, 0, tid, tile);
  } else if (id < 576){
    int l = id - 288;
    transpose_tile(w1, w1T, 128, 384, l % 6, (l / 6) % 2, l / 12, tid, tile);
  } else if (id < 864){
    int l = id - 576;
    transpose_tile(w2, w2T, 384, 128, l % 2, (l / 2) % 6, l / 12, tid, tile);
  } else if (id < 1248){
    // fold: W64[d][h*24+e] = sum_dh head[d][h*128+dh]*choice[e][dh], 2 d's per block
    int l = id - 864;                       // 0..383
    const int sub = tid >> 7, lt = tid & 127;
    const int d = l * 2 + sub;
    double* hrow = buf + sub * 768;
    for (int i = lt; i < 768; i += 128) hrow[i] = (double)head[(long)d * 768 + i];
    __syncthreads();
    for (int c = lt; c < 144; c += 128){
      int h = c / 24, e = c % 24;
      double a = 0.0;
      const double* hr = hrow + h * 128;
      const float* ch = choice + e * 128;
#pragma unroll 8
      for (int k = 0; k < 128; k++) a += hr[k] * (double)ch[k];
      W64[(long)d * 144 + c] = a;
    }
  } else {
    const long l = id - 1248;               // 0..6143
    const long i = (l * 256 + tid) * 4;
    floatx4 v = *(const floatx4*)(x + i);
    short4v o;
#pragma unroll
    for (int u = 0; u < 4; u++) o[u] = (short)f2bf(v[u]);
    *(short4v*)(xb + i) = o;
  }
}

// -------- bf16 MFMA GEMM body (BT input), 128x128 tile, BK=64; OUTF=1 -> fp32 C -----------
template<int OUTF>
DEV void gemm_body(const unsigned short* __restrict__ A, const unsigned short* __restrict__ BT,
                   unsigned short* __restrict__ C, float* __restrict__ Cf, int N, int K,
                   unsigned short* As, unsigned short* Bs, int m0, int n0, int tid)
{
  const int lane = tid & 63;
  const int w = tid >> 6;
  const int wy = w >> 1, wx = w & 1;

  floatx4 acc[4][4];
  {
    floatx4 z4 = {0.f, 0.f, 0.f, 0.f};
#pragma unroll
    for (int i = 0; i < 4; i++)
#pragma unroll
      for (int j = 0; j < 4; j++) acc[i][j] = z4;
  }

  const int rsub = lane >> 3;
  const int kcol = (lane & 7) * 8;

  for (int k0 = 0; k0 < K; k0 += 64){
#pragma unroll
    for (int i = 0; i < 4; i++){
      const int inst = w * 4 + i;
      const int rr = inst * 8 + rsub;
      gll16(A + (long)(m0 + rr) * K + k0 + kcol, &As[inst * 512], lane);
      gll16(BT + (long)(n0 + rr) * K + k0 + kcol, &Bs[inst * 512], lane);
    }
    __syncthreads();
#pragma unroll
    for (int ks = 0; ks < 2; ++ks){
      const int kb = ks * 32 + (lane >> 4) * 8;
      short8 af[4], bfr[4];
#pragma unroll
      for (int mi = 0; mi < 4; mi++) af[mi]  = *(const short8*)&As[(wy * 64 + mi * 16 + (lane & 15)) * 64 + kb];
#pragma unroll
      for (int ni = 0; ni < 4; ni++) bfr[ni] = *(const short8*)&Bs[(wx * 64 + ni * 16 + (lane & 15)) * 64 + kb];
#pragma unroll
      for (int mi = 0; mi < 4; mi++)
#pragma unroll
        for (int ni = 0; ni < 4; ni++)
          acc[mi][ni] = __builtin_amdgcn_mfma_f32_16x16x32_bf16(af[mi], bfr[ni], acc[mi][ni], 0, 0, 0);
    }
    __syncthreads();
  }

  const int ml = lane & 15;
  const int rq = (lane >> 4) * 4;
#pragma unroll
  for (int mi = 0; mi < 4; mi++){
    const int rowb = m0 + wy * 64 + mi * 16 + rq;
#pragma unroll
    for (int ni = 0; ni < 4; ni++){
      const int col = n0 + wx * 64 + ni * 16 + ml;
#pragma unroll
      for (int r = 0; r < 4; r++){
        float v = acc[mi][ni][r];
        if (OUTF) Cf[(long)(rowb + r) * N + col] = v;
        else      C[(long)(rowb + r) * N + col] = f2bf(v);
      }
    }
  }
}

// -------- gates matmul body: P[kseg][8192][144] = x(64-row tile) @ W(192-k seg), fp64 -----
DEV void gates_body(const float* __restrict__ xg, const double* __restrict__ W,
                    double* __restrict__ P, float* xs, double* Ws,
                    int row0, int ksegIdx, int tid)
{
  const int tx = tid & 15;
  const int ty = tid >> 4;
  const int kseg = ksegIdx * 192;

  double acc[4][9];
#pragma unroll
  for (int i = 0; i < 4; i++)
#pragma unroll
    for (int j = 0; j < 9; j++) acc[i][j] = 0.0;

  for (int kc = 0; kc < 192; kc += 32){
    const int k0 = kseg + kc;
    {
      int rr = tid & 63;
      int kk8 = (tid >> 6) * 8;
      const float* src = xg + (long)(row0 + rr) * 768 + k0 + kk8;
      floatx4 v0 = *(const floatx4*)src;
      floatx4 v1 = *(const floatx4*)(src + 4);
#pragma unroll
      for (int u = 0; u < 4; u++) xs[(kk8 + u) * 64 + rr] = v0[u];
#pragma unroll
      for (int u = 0; u < 4; u++) xs[(kk8 + 4 + u) * 64 + rr] = v1[u];
    }
    for (int f = tid; f < 4608; f += 256) Ws[f] = W[(long)(k0 + f / 144) * 144 + (f % 144)];
    __syncthreads();
#pragma unroll 2
    for (int kk = 0; kk < 32; kk++){
      floatx4 xv = *(const floatx4*)&xs[kk * 64 + ty * 4];
      double xd[4];
#pragma unroll
      for (int i = 0; i < 4; i++) xd[i] = (double)xv[i];
#pragma unroll
      for (int j = 0; j < 9; j++){
        double wv = Ws[kk * 144 + tx + 16 * j];
#pragma unroll
        for (int i = 0; i < 4; i++) acc[i][j] += xd[i] * wv;
      }
    }
    __syncthreads();
  }
  double* dstseg = P + (long)ksegIdx * 8192 * 144;
#pragma unroll
  for (int i = 0; i < 4; i++){
    double* dst = dstseg + (long)(row0 + ty * 4 + i) * 144;
#pragma unroll
    for (int j = 0; j < 9; j++) dst[tx + 16 * j] = acc[i][j];
  }
}

// -------- fused head-GEMM + gates: [0,384) gemm0 tiles, [384,896) gates tiles -------------
// Independent outputs (x1 vs P); co-dispatch overlaps MFMA-heavy and fp64-VALU-heavy blocks.
__global__ __launch_bounds__(256, 2) void k_main0(const unsigned short* __restrict__ xb,
    const unsigned short* __restrict__ headT, unsigned short* __restrict__ x1,
    const float* __restrict__ xg, const double* __restrict__ W, double* __restrict__ P)
{
  __shared__ double lds[5632];   // 45056 B union: gemm 32KB | gates 8KB + 36.9KB
  const int id = blockIdx.x, tid = threadIdx.x;
  if (id < 384){
    unsigned short* As = (unsigned short*)lds;
    unsigned short* Bs = As + 128 * 64;
    gemm_body<0>(xb, headT, x1, nullptr, 768, 768, As, Bs, (id & 63) * 128, (id >> 6) * 128, tid);
  } else {
    const int id2 = id - 384;    // 0..511
    float* xs = (float*)lds;
    double* Ws = (double*)((char*)lds + 8192);
    gates_body(xg, W, P, xs, Ws, (id2 & 127) * 64, id2 >> 7, tid);
  }
}

// -------- fused reduce + softmax: logits from 4 partials, softmax, write gatesT[be][n] ----
__global__ __launch_bounds__(256) void k_softmax(const double* __restrict__ P,
                                                 double* __restrict__ gatesT)
{
  const int gid = blockIdx.x * 256 + threadIdx.x;   // < 49152
  const int R = gid / 6, h = gid % 6;
  const int b = R >> 10, s = R & 1023;
  const int n = s * 6 + h;
  const long S = (long)8192 * 144;
  const long base = (long)R * 144 + h * 24;
  double l[24];
#pragma unroll
  for (int e = 0; e < 24; e++){
    const long o = base + e;
    l[e] = (P[o] + P[S + o]) + (P[2 * S + o] + P[3 * S + o]);
  }
  double m = l[0];
#pragma unroll
  for (int e = 1; e < 24; e++) m = fmax(m, l[e]);
  double ssum = 0.0;
#pragma unroll
  for (int e = 0; e < 24; e++) ssum += exp(l[e] - m);
  double is = 1.0 / ssum;
#pragma unroll
  for (int e = 0; e < 24; e++)
    gatesT[((long)(b * 24 + e)) * 6144 + n] = exp(l[e] - m) * is;
}

// -------- top-K=1024 of 6144 per (b,e), exact fp64, jax tie semantics ---------------------
DEV int blk_reduce(int v, volatile int* sbuf, int tid){
#pragma unroll
  for (int off = 32; off > 0; off >>= 1) v += __shfl_down(v, off);
  __syncthreads();
  if ((tid & 63) == 0) sbuf[tid >> 6] = v;
  __syncthreads();
  return sbuf[0] + sbuf[1] + sbuf[2] + sbuf[3];
}

__global__ __launch_bounds__(256) void k_topk(const double* __restrict__ gatesT,
                                              int* __restrict__ Kidx, float* __restrict__ Gval,
                                              int* __restrict__ cnt, unsigned short* __restrict__ inv)
{
  __shared__ int sbuf[4];
  __shared__ int s_pos;
  const int tid = threadIdx.x;
  const int be = blockIdx.x;
  const int b = be / 24, e = be % 24;
  const double* g = gatesT + (long)be * 6144;

  unsigned long long key[24];
#pragma unroll
  for (int j = 0; j < 24; j++)
    key[j] = (unsigned long long)__double_as_longlong(g[tid + 256 * j]);

  unsigned long long lo = 0ull, hi = ~0ull;
  for (int it = 0; it < 64; ++it){
    if (hi - lo <= 1ull) break;
    unsigned long long mid = lo + ((hi - lo) >> 1);
    int c = 0;
#pragma unroll
    for (int j = 0; j < 24; j++) c += (key[j] > mid) ? 1 : 0;
    c = blk_reduce(c, sbuf, tid);
    if (c >= 1024) lo = mid; else hi = mid;
  }
  const unsigned long long T = hi;
  int cg = 0;
#pragma unroll
  for (int j = 0; j < 24; j++) cg += (key[j] > T) ? 1 : 0;
  cg = blk_reduce(cg, sbuf, tid);
  const int need = 1024 - cg;

  int lo2 = 0, hi2 = 6144;
  for (int it = 0; it < 13; ++it){
    if (hi2 - lo2 <= 1) break;
    int mid = (lo2 + hi2) >> 1;
    int c = 0;
#pragma unroll
    for (int j = 0; j < 24; j++) c += (key[j] == T && (tid + 256 * j) < mid) ? 1 : 0;
    c = blk_reduce(c, sbuf, tid);
    if (c >= need) hi2 = mid; else lo2 = mid;
  }
  const int m = hi2;

  if (tid == 0) s_pos = 0;
  __syncthreads();
#pragma unroll
  for (int j = 0; j < 24; j++){
    int n = tid + 256 * j;
    bool sel = (key[j] > T) || (key[j] == T && n < m);
    if (sel){
      int slot = atomicAdd(&s_pos, 1);
      Kidx[(long)be * 1024 + slot] = n;
      Gval[(long)be * 1024 + slot] = (float)__longlong_as_double((long long)key[j]);
      int t = b * 6144 + n;
      int p = atomicAdd(&cnt[t], 1);
      inv[(long)t * 24 + p] = (unsigned short)(e * 1024 + slot);
    }
  }
}

// -------- merge GEMM (fp32 out) -----------------------------------------------------------
__global__ __launch_bounds__(256, 2) void k_gemm2(const unsigned short* __restrict__ A,
    const unsigned short* __restrict__ BT, float* __restrict__ Cf)
{
  __shared__ unsigned short As[128 * 64];
  __shared__ unsigned short Bs[128 * 64];
  gemm_body<1>(A, BT, nullptr, Cf, 768, 768, As, Bs,
               (int)blockIdx.x * 128, (int)blockIdx.y * 128, (int)threadIdx.x);
}

// -------- fused per-expert FFN: Y[be][k][dh] = gate * (silu(gather(x1)@w1) @ w2), bf16 ----
// grid (8 m-tiles of 128 rows, 192 be). block 256. LDS exactly 80 KB -> 2 blocks/CU.
// All LDS XOR-chunk-swizzled (16B chunks): As/W1c pos = chunk^(row&15); W2c pos = chunk^(row&7);
// Hc pos = chunk^(tokrow&7).
__global__ __launch_bounds__(256, 2) void k_ffn(const unsigned short* __restrict__ x1,
    const unsigned short* __restrict__ w1T, const unsigned short* __restrict__ w2T,
    const int* __restrict__ KidxAll, const float* __restrict__ GvalAll,
    unsigned short* __restrict__ Y)
{
  __shared__ unsigned short As[128 * 128];   // 32 KB [row][k]
  __shared__ unsigned short W1c[64 * 128];   // 16 KB [hcol][k]
  __shared__ unsigned short W2c[128 * 64];   // 16 KB [out][hchunk]
  __shared__ unsigned short Hc[128 * 64];    // 16 KB [tokrow][hcol]
  const int tid = threadIdx.x, lane = tid & 63, w = tid >> 6;
  const int tx = lane & 15, quad = lane >> 4;
  const int mt = blockIdx.x;
  const int be = blockIdx.y;
  const int b = be / 24, e = be % 24;
  const int* idx = KidxAll + (long)be * 1024 + mt * 128;
  const float* scl = GvalAll + (long)be * 1024 + mt * 128;
  const unsigned short* A   = x1  + (long)b * 6144 * 128;
  const unsigned short* w1e = w1T + (long)e * 384 * 128;
  const unsigned short* w2e = w2T + (long)e * 128 * 384;

  {
    const int r0 = w * 32;
#pragma unroll
    for (int i = 0; i < 8; i++){
      int rr = r0 + i * 4 + quad;
      int c = tx ^ (rr & 15);
      gll16(A + (long)idx[rr] * 128 + c * 8, &As[(r0 + i * 4) * 128], lane);
    }
  }

  floatx4 Yt[2][8];   // [mf out-tile][nf tokrow-tile]
  {
    floatx4 z4 = {0.f, 0.f, 0.f, 0.f};
#pragma unroll
    for (int i = 0; i < 2; i++)
#pragma unroll
      for (int j = 0; j < 8; j++) Yt[i][j] = z4;
  }

  for (int nc = 0; nc < 6; ++nc){
    {
      const int r0 = w * 16;
#pragma unroll
      for (int i = 0; i < 4; i++){
        int lr = r0 + i * 4 + quad;
        int c = tx ^ (lr & 15);
        gll16(w1e + (long)(nc * 64 + lr) * 128 + c * 8, &W1c[(r0 + i * 4) * 128], lane);
      }
    }
    {
      const int r0 = w * 32;
#pragma unroll
      for (int i = 0; i < 4; i++){
        int rr = r0 + i * 8 + (lane >> 3);
        int c = (lane & 7) ^ (rr & 7);
        gll16(w2e + (long)rr * 384 + nc * 64 + c * 8, &W2c[(r0 + i * 8) * 64], lane);
      }
    }
    __syncthreads();

    // stage1: h = silu(As @ W1c^T); wave w -> rows w*32..+32 (2 mi) x 64 hcols (4 nf)
    floatx4 h4[2][4];
    {
      floatx4 z4 = {0.f, 0.f, 0.f, 0.f};
#pragma unroll
      for (int i = 0; i < 2; i++)
#pragma unroll
        for (int j = 0; j < 4; j++) h4[i][j] = z4;
    }
#pragma unroll
    for (int ks = 0; ks < 4; ++ks){
      const int chunk = ks * 4 + quad;
      const int pos = chunk ^ tx;
      short8 af[2];
#pragma unroll
      for (int mi = 0; mi < 2; ++mi)
        af[mi] = *(const short8*)&As[(w * 32 + mi * 16 + tx) * 128 + pos * 8];
#pragma unroll
      for (int nf = 0; nf < 4; ++nf){
        short8 bfr = *(const short8*)&W1c[(nf * 16 + tx) * 128 + pos * 8];
#pragma unroll
        for (int mi = 0; mi < 2; ++mi)
          h4[mi][nf] = __builtin_amdgcn_mfma_f32_16x16x32_bf16(af[mi], bfr, h4[mi][nf], 0, 0, 0);
      }
    }
#pragma unroll
    for (int mi = 0; mi < 2; ++mi){
#pragma unroll
      for (int nf = 0; nf < 4; ++nf){
        const int hchunk = nf * 2 + (tx >> 3);
        const int hoff = tx & 7;
#pragma unroll
        for (int r = 0; r < 4; r++){
          float v = silu(h4[mi][nf][r]);
          const int trow = w * 32 + mi * 16 + quad * 4 + r;
          Hc[trow * 64 + (hchunk ^ (trow & 7)) * 8 + hoff] = f2bf(v);
        }
      }
    }
    __syncthreads();

    // stage2: YT[out][tokrow] += W2c[out][hcol] x Hc[tokrow][hcol]; wave w -> outs w*32..+32
#pragma unroll
    for (int ks = 0; ks < 2; ++ks){
      const int chunk2 = ks * 4 + quad;
      const int posx = chunk2 ^ (tx & 7);
      short8 a2[2], b2[8];
#pragma unroll
      for (int mf = 0; mf < 2; ++mf)
        a2[mf] = *(const short8*)&W2c[(w * 32 + mf * 16 + tx) * 64 + posx * 8];
#pragma unroll
      for (int nf = 0; nf < 8; ++nf)
        b2[nf] = *(const short8*)&Hc[(nf * 16 + tx) * 64 + posx * 8];
#pragma unroll
      for (int mf = 0; mf < 2; ++mf)
#pragma unroll
        for (int nf = 0; nf < 8; ++nf)
          Yt[mf][nf] = __builtin_amdgcn_mfma_f32_16x16x32_bf16(a2[mf], b2[nf], Yt[mf][nf], 0, 0, 0);
    }
    __syncthreads();
  }

#pragma unroll
  for (int nf = 0; nf < 8; ++nf){
    const int rb = nf * 16 + tx;
    const float g = scl[rb];
    unsigned short* dst = Y + ((long)be * 1024 + mt * 128 + rb) * 128 + w * 32 + quad * 4;
#pragma unroll
    for (int mf = 0; mf < 2; ++mf){
      short4v v;
#pragma unroll
      for (int r = 0; r < 4; r++) v[r] = (short)f2bf(Yt[mf][nf][r] * g);
      *(short4v*)(dst + mf * 16) = v;
    }
  }
}

// -------- combine: xout[t][:] = sum over picks of Y[e][slot][:] (gates pre-applied) -------
__global__ __launch_bounds__(256) void k_combine(const int* __restrict__ cnt,
    const unsigned short* __restrict__ inv, const unsigned short* __restrict__ Y,
    unsigned short* __restrict__ xout)
{
  const int t = blockIdx.x * 4 + (threadIdx.x >> 6);   // token id, < 49152
  const int lane = threadIdx.x & 63;
  const int b = t / 6144;
  const int c = cnt[t];
  float a0 = 0.f, a1 = 0.f;
  for (int p = 0; p < c; ++p){
    int code = inv[(long)t * 24 + p];
    int e = code >> 10, slot = code & 1023;
    const unsigned short* y = Y + (((long)(b * 24 + e) * 1024 + slot) << 7) + lane * 2;
    a0 += bf2f(y[0]); a1 += bf2f(y[1]);
  }
  unsigned short* o = xout + ((long)t << 7) + lane * 2;
  o[0] = f2bf(a0); o[1] = f2bf(a1);
}

// ==========================================================================================
extern "C" void kernel_launch(void* const* d_in, const int* in_sizes, int n_in,
                              void* d_out, int out_size, void* d_ws, size_t ws_size,
                              hipStream_t stream)
{
  const float* x      = (const float*)d_in[0];
  const float* choice = (const float*)d_in[1];
  const float* w1     = (const float*)d_in[2];
  const float* w2     = (const float*)d_in[3];
  const float* head   = (const float*)d_in[4];
  const float* merge  = (const float*)d_in[5];
  float* out = (float*)d_out;
  (void)in_sizes; (void)n_in; (void)out_size; (void)ws_size;

  char* p = (char*)d_ws;
  auto alloc = [&p](size_t bytes) -> void* {
    void* q = (void*)p; p += (bytes + 255) & ~(size_t)255; return q;
  };

  unsigned short* headT = (unsigned short*)alloc((size_t)768 * 768 * 2);
  unsigned short* mergeT= (unsigned short*)alloc((size_t)768 * 768 * 2);
  unsigned short* w1T   = (unsigned short*)alloc((size_t)24 * 384 * 128 * 2);
  unsigned short* w2T   = (unsigned short*)alloc((size_t)24 * 128 * 384 * 2);
  double* W64           = (double*)alloc((size_t)768 * 144 * 8);
  int* Kidx             = (int*)alloc((size_t)192 * 1024 * 4);
  float* Gval           = (float*)alloc((size_t)192 * 1024 * 4);
  int* cnt              = (int*)alloc((size_t)49152 * 4);
  unsigned short* inv   = (unsigned short*)alloc((size_t)49152 * 24 * 2);
  unsigned short* xb    = (unsigned short*)alloc((size_t)8192 * 768 * 2);   // 12.58 MB
  unsigned short* x1    = (unsigned short*)alloc((size_t)8192 * 768 * 2);   // 12.58 MB
  // big region (50.33 MB): Y for ffn; before topk it hosts P (37.75) + gatesT (9.44)
  unsigned short* Y     = (unsigned short*)alloc((size_t)192 * 1024 * 128 * 2);
  double* P             = (double*)Y;                                             // [4][8192][144]
  double* gatesT        = (double*)((char*)Y + (size_t)4 * 8192 * 144 * 8);       // 9.44 MB
  unsigned short* xout  = xb;            // xb dead after k_main0; xout written by combine

  hipMemsetAsync(cnt, 0, (size_t)49152 * 4, stream);
  k_prep<<<dim3(7392), 256, 0, stream>>>(x, choice, w1, w2, head, merge,
                                         xb, headT, mergeT, w1T, w2T, W64);
  k_main0<<<dim3(896), 256, 0, stream>>>(xb, headT, x1, x, W64, P);
  k_softmax<<<dim3(192), 256, 0, stream>>>(P, gatesT);
  k_topk<<<dim3(192), 256, 0, stream>>>(gatesT, Kidx, Gval, cnt, inv);
  // P/gatesT dead; Y region free for ffn
  k_ffn<<<dim3(8, 192, 1), 256, 0, stream>>>(x1, w1T, w2T, Kidx, Gval, Y);
  k_combine<<<dim3(12288), 256, 0, stream>>>(cnt, inv, Y, xout);
  k_gemm2<<<dim3(64, 6, 1), 256, 0, stream>>>(xout, mergeT, out);
}

// Round 11
// 384.362 us; speedup vs baseline: 1.8049x; 1.0170x over previous
//
#include <hip/hip_runtime.h>
#include <stdint.h>
#include <math.h>

typedef __attribute__((ext_vector_type(8))) short short8;
typedef __attribute__((ext_vector_type(4))) short short4v;
typedef __attribute__((ext_vector_type(4))) float floatx4;
typedef __attribute__((ext_vector_type(2))) float floatx2;

#define DEV static __device__ __forceinline__

DEV float bf2f(unsigned short u){ union { unsigned int i; float f; } c; c.i = ((unsigned int)u) << 16; return c.f; }
DEV unsigned short f2bf(float f){ union { float f; unsigned int i; } c; c.f = f; unsigned int u = c.i; u += 0x7fffu + ((u >> 16) & 1u); return (unsigned short)(u >> 16); }

#if defined(__has_builtin)
#if __has_builtin(__builtin_amdgcn_global_load_lds)
#define USE_GLL 1
#endif
#if __has_builtin(__builtin_amdgcn_exp2f) && __has_builtin(__builtin_amdgcn_rcpf)
#define FAST_SILU 1
#endif
#endif
#ifndef USE_GLL
#define USE_GLL 0
#endif
#ifndef FAST_SILU
#define FAST_SILU 0
#endif

// async global->LDS, 16B per lane. ldsbase is wave-uniform; HW writes base + lane*16.
DEV void gll16(const unsigned short* g, unsigned short* ldsbase, int lane){
#if USE_GLL
  __builtin_amdgcn_global_load_lds((const __attribute__((address_space(1))) void*)g,
                                   (__attribute__((address_space(3))) void*)ldsbase, 16, 0, 0);
#else
  *(short8*)(ldsbase + lane * 8) = *(const short8*)g;
#endif
}

DEV float silu(float v){
#if FAST_SILU
  float ex = __builtin_amdgcn_exp2f(v * -1.44269504088896f);
  return v * __builtin_amdgcn_rcpf(1.f + ex);   // rcp err ~1ulp fp32, hidden by bf16 round
#else
  return v / (1.f + __expf(-v));
#endif
}

// -------- transpose tile helper: out_bf16[C][R] = in_f32[R][C] ----------------------------
DEV void transpose_tile(const float* in, unsigned short* out, int R, int C,
                        int bx, int by, int bz, int tid, unsigned short* tile)
{
  const long boff = (long)bz * (long)R * (long)C;
  in += boff; out += boff;
  const int c0 = bx * 64, r0 = by * 64;
  const int rr = tid >> 4;
  const int c4 = (tid & 15) * 4;
#pragma unroll
  for (int i = 0; i < 4; i++){
    int r = rr + i * 16;
    floatx4 v = *(const floatx4*)(in + (long)(r0 + r) * C + c0 + c4);
#pragma unroll
    for (int u = 0; u < 4; u++) tile[r * 68 + c4 + u] = f2bf(v[u]);
  }
  __syncthreads();
#pragma unroll
  for (int i = 0; i < 4; i++){
    int cc = rr + i * 16;
    short4v v;
#pragma unroll
    for (int u = 0; u < 4; u++) v[u] = (short)tile[(c4 + u) * 68 + cc];
    *(short4v*)(out + (long)(c0 + cc) * R + r0 + c4) = v;
  }
}

// -------- fused prep: 4 transposes + fold + xconv, flat block decode ----------------------
__global__ __launch_bounds__(256) void k_prep(const float* __restrict__ x,
    const float* __restrict__ choice, const float* __restrict__ w1,
    const float* __restrict__ w2, const float* __restrict__ head,
    const float* __restrict__ merge,
    unsigned short* __restrict__ xb, unsigned short* __restrict__ headT,
    unsigned short* __restrict__ mergeT, unsigned short* __restrict__ w1T,
    unsigned short* __restrict__ w2T, double* __restrict__ W64)
{
  __shared__ double buf[1536];   // 12.3 KB: transpose tile (8.7 KB) or fold hrow (12.3 KB)
  unsigned short* tile = (unsigned short*)buf;
  const int id = blockIdx.x, tid = threadIdx.x;
  if (id < 144){
    transpose_tile(head, headT, 768, 768, id % 12, id / 12, 0, tid, tile);
  } else if (id < 288){
    int l = id - 144;
    transpose_tile(merge, mergeT, 768, 768, l % 12, l / 12, 0, tid, tile);
  } else if (id < 576){
    int l = id - 288;
    transpose_tile(w1, w1T, 128, 384, l % 6, (l / 6) % 2, l / 12, tid, tile);
  } else if (id < 864){
    int l = id - 576;
    transpose_tile(w2, w2T, 384, 128, l % 2, (l / 2) % 6, l / 12, tid, tile);
  } else if (id < 1248){
    int l = id - 864;                       // 0..383, fold: 2 d's per block
    const int sub = tid >> 7, lt = tid & 127;
    const int d = l * 2 + sub;
    double* hrow = buf + sub * 768;
    for (int i = lt; i < 768; i += 128) hrow[i] = (double)head[(long)d * 768 + i];
    __syncthreads();
    for (int c = lt; c < 144; c += 128){
      int h = c / 24, e = c % 24;
      double a = 0.0;
      const double* hr = hrow + h * 128;
      const float* ch = choice + e * 128;
#pragma unroll 8
      for (int k = 0; k < 128; k++) a += hr[k] * (double)ch[k];
      W64[(long)d * 144 + c] = a;
    }
  } else {
    const long l = id - 1248;               // 0..6143
    const long i = (l * 256 + tid) * 4;
    floatx4 v = *(const floatx4*)(x + i);
    short4v o;
#pragma unroll
    for (int u = 0; u < 4; u++) o[u] = (short)f2bf(v[u]);
    *(short4v*)(xb + i) = o;
  }
}

// -------- bf16 MFMA GEMM body (BT input), 128x128 tile, BK=64; OUTF=1 -> fp32 C -----------
template<int OUTF>
DEV void gemm_body(const unsigned short* __restrict__ A, const unsigned short* __restrict__ BT,
                   unsigned short* __restrict__ C, float* __restrict__ Cf, int N, int K,
                   unsigned short* As, unsigned short* Bs, int m0, int n0, int tid)
{
  const int lane = tid & 63;
  const int w = tid >> 6;
  const int wy = w >> 1, wx = w & 1;

  floatx4 acc[4][4];
  {
    floatx4 z4 = {0.f, 0.f, 0.f, 0.f};
#pragma unroll
    for (int i = 0; i < 4; i++)
#pragma unroll
      for (int j = 0; j < 4; j++) acc[i][j] = z4;
  }

  const int rsub = lane >> 3;
  const int kcol = (lane & 7) * 8;

  for (int k0 = 0; k0 < K; k0 += 64){
#pragma unroll
    for (int i = 0; i < 4; i++){
      const int inst = w * 4 + i;
      const int rr = inst * 8 + rsub;
      gll16(A + (long)(m0 + rr) * K + k0 + kcol, &As[inst * 512], lane);
      gll16(BT + (long)(n0 + rr) * K + k0 + kcol, &Bs[inst * 512], lane);
    }
    __syncthreads();
#pragma unroll
    for (int ks = 0; ks < 2; ++ks){
      const int kb = ks * 32 + (lane >> 4) * 8;
      short8 af[4], bfr[4];
#pragma unroll
      for (int mi = 0; mi < 4; mi++) af[mi]  = *(const short8*)&As[(wy * 64 + mi * 16 + (lane & 15)) * 64 + kb];
#pragma unroll
      for (int ni = 0; ni < 4; ni++) bfr[ni] = *(const short8*)&Bs[(wx * 64 + ni * 16 + (lane & 15)) * 64 + kb];
#pragma unroll
      for (int mi = 0; mi < 4; mi++)
#pragma unroll
        for (int ni = 0; ni < 4; ni++)
          acc[mi][ni] = __builtin_amdgcn_mfma_f32_16x16x32_bf16(af[mi], bfr[ni], acc[mi][ni], 0, 0, 0);
    }
    __syncthreads();
  }

  const int ml = lane & 15;
  const int rq = (lane >> 4) * 4;
#pragma unroll
  for (int mi = 0; mi < 4; mi++){
    const int rowb = m0 + wy * 64 + mi * 16 + rq;
#pragma unroll
    for (int ni = 0; ni < 4; ni++){
      const int col = n0 + wx * 64 + ni * 16 + ml;
#pragma unroll
      for (int r = 0; r < 4; r++){
        float v = acc[mi][ni][r];
        if (OUTF) Cf[(long)(rowb + r) * N + col] = v;
        else      C[(long)(rowb + r) * N + col] = f2bf(v);
      }
    }
  }
}

// -------- gates matmul body: P[kseg][8192][144], 32-row tiles for 4 blocks/CU -------------
// LDS: xs 4KB + Ws 36KB = 40960 B exactly -> 4 blocks/CU (160 KB), 16 waves/CU.
DEV void gates_body(const float* __restrict__ xg, const double* __restrict__ W,
                    double* __restrict__ P, float* xs, double* Ws,
                    int row0, int ksegIdx, int tid)
{
  const int tx = tid & 15;
  const int ty = tid >> 4;
  const int kseg = ksegIdx * 192;

  double acc[2][9];
#pragma unroll
  for (int i = 0; i < 2; i++)
#pragma unroll
    for (int j = 0; j < 9; j++) acc[i][j] = 0.0;

  for (int kc = 0; kc < 192; kc += 32){
    const int k0 = kseg + kc;
    {
      int rr = tid & 31;                 // row 0..31
      int kk4 = (tid >> 5) * 4;          // 0,4,..,28
      floatx4 v = *(const floatx4*)(xg + (long)(row0 + rr) * 768 + k0 + kk4);
#pragma unroll
      for (int u = 0; u < 4; u++) xs[(kk4 + u) * 32 + rr] = v[u];
    }
    for (int f = tid; f < 4608; f += 256) Ws[f] = W[(long)(k0 + f / 144) * 144 + (f % 144)];
    __syncthreads();
#pragma unroll 2
    for (int kk = 0; kk < 32; kk++){
      floatx2 xv = *(const floatx2*)&xs[kk * 32 + ty * 2];
      double x0 = (double)xv[0], x1d = (double)xv[1];
#pragma unroll
      for (int j = 0; j < 9; j++){
        double wv = Ws[kk * 144 + tx + 16 * j];
        acc[0][j] += x0 * wv;
        acc[1][j] += x1d * wv;
      }
    }
    __syncthreads();
  }
  double* dstseg = P + (long)ksegIdx * 8192 * 144;
#pragma unroll
  for (int i = 0; i < 2; i++){
    double* dst = dstseg + (long)(row0 + ty * 2 + i) * 144;
#pragma unroll
    for (int j = 0; j < 9; j++) dst[tx + 16 * j] = acc[i][j];
  }
}

// -------- fused gates + head-GEMM: [0,1024) gates tiles FIRST, [1024,1408) gemm -----------
// Gates (fp64, long pole) dispatched first; gemm (MFMA) fills the tail. LDS 40 KB union.
__global__ __launch_bounds__(256, 4) void k_main0(const unsigned short* __restrict__ xb,
    const unsigned short* __restrict__ headT, unsigned short* __restrict__ x1,
    const float* __restrict__ xg, const double* __restrict__ W, double* __restrict__ P)
{
  __shared__ double lds[5120];   // 40960 B: gates 4KB xs + 36KB Ws | gemm 32KB As+Bs
  const int id = blockIdx.x, tid = threadIdx.x;
  if (id < 1024){
    float* xs = (float*)lds;
    double* Ws = (double*)((char*)lds + 4096);
    gates_body(xg, W, P, xs, Ws, (id & 255) * 32, id >> 8, tid);
  } else {
    const int id2 = id - 1024;   // 0..383
    unsigned short* As = (unsigned short*)lds;
    unsigned short* Bs = As + 128 * 64;
    gemm_body<0>(xb, headT, x1, nullptr, 768, 768, As, Bs, (id2 & 63) * 128, (id2 >> 6) * 128, tid);
  }
}

// -------- fused reduce + softmax: logits from 4 partials, softmax, write gatesT[be][n] ----
__global__ __launch_bounds__(256) void k_softmax(const double* __restrict__ P,
                                                 double* __restrict__ gatesT)
{
  const int gid = blockIdx.x * 256 + threadIdx.x;   // < 49152
  const int R = gid / 6, h = gid % 6;
  const int b = R >> 10, s = R & 1023;
  const int n = s * 6 + h;
  const long S = (long)8192 * 144;
  const long base = (long)R * 144 + h * 24;
  double l[24];
#pragma unroll
  for (int e = 0; e < 24; e++){
    const long o = base + e;
    l[e] = (P[o] + P[S + o]) + (P[2 * S + o] + P[3 * S + o]);
  }
  double m = l[0];
#pragma unroll
  for (int e = 1; e < 24; e++) m = fmax(m, l[e]);
  double ssum = 0.0;
#pragma unroll
  for (int e = 0; e < 24; e++){ l[e] = exp(l[e] - m); ssum += l[e]; }
  double is = 1.0 / ssum;
#pragma unroll
  for (int e = 0; e < 24; e++)
    gatesT[((long)(b * 24 + e)) * 6144 + n] = l[e] * is;
}

// -------- top-K=1024 of 6144 per (b,e), exact fp64, jax tie semantics ---------------------
DEV int blk_reduce(int v, volatile int* sbuf, int tid){
#pragma unroll
  for (int off = 32; off > 0; off >>= 1) v += __shfl_down(v, off);
  __syncthreads();
  if ((tid & 63) == 0) sbuf[tid >> 6] = v;
  __syncthreads();
  return sbuf[0] + sbuf[1] + sbuf[2] + sbuf[3];
}

__global__ __launch_bounds__(256) void k_topk(const double* __restrict__ gatesT,
                                              int* __restrict__ Kidx, float* __restrict__ Gval,
                                              int* __restrict__ cnt, unsigned short* __restrict__ inv)
{
  __shared__ int sbuf[4];
  __shared__ int s_pos;
  const int tid = threadIdx.x;
  const int be = blockIdx.x;
  const int b = be / 24, e = be % 24;
  const double* g = gatesT + (long)be * 6144;

  unsigned long long key[24];
#pragma unroll
  for (int j = 0; j < 24; j++)
    key[j] = (unsigned long long)__double_as_longlong(g[tid + 256 * j]);

  unsigned long long lo = 0ull, hi = ~0ull;
  for (int it = 0; it < 64; ++it){
    if (hi - lo <= 1ull) break;
    unsigned long long mid = lo + ((hi - lo) >> 1);
    int c = 0;
#pragma unroll
    for (int j = 0; j < 24; j++) c += (key[j] > mid) ? 1 : 0;
    c = blk_reduce(c, sbuf, tid);
    if (c >= 1024) lo = mid; else hi = mid;
  }
  const unsigned long long T = hi;
  int cg = 0;
#pragma unroll
  for (int j = 0; j < 24; j++) cg += (key[j] > T) ? 1 : 0;
  cg = blk_reduce(cg, sbuf, tid);
  const int need = 1024 - cg;

  int lo2 = 0, hi2 = 6144;
  for (int it = 0; it < 13; ++it){
    if (hi2 - lo2 <= 1) break;
    int mid = (lo2 + hi2) >> 1;
    int c = 0;
#pragma unroll
    for (int j = 0; j < 24; j++) c += (key[j] == T && (tid + 256 * j) < mid) ? 1 : 0;
    c = blk_reduce(c, sbuf, tid);
    if (c >= need) hi2 = mid; else lo2 = mid;
  }
  const int m = hi2;

  if (tid == 0) s_pos = 0;
  __syncthreads();
#pragma unroll
  for (int j = 0; j < 24; j++){
    int n = tid + 256 * j;
    bool sel = (key[j] > T) || (key[j] == T && n < m);
    if (sel){
      int slot = atomicAdd(&s_pos, 1);
      Kidx[(long)be * 1024 + slot] = n;
      Gval[(long)be * 1024 + slot] = (float)__longlong_as_double((long long)key[j]);
      int t = b * 6144 + n;
      int p = atomicAdd(&cnt[t], 1);
      inv[(long)t * 24 + p] = (unsigned short)(e * 1024 + slot);
    }
  }
}

// -------- merge GEMM (fp32 out) -----------------------------------------------------------
__global__ __launch_bounds__(256, 2) void k_gemm2(const unsigned short* __restrict__ A,
    const unsigned short* __restrict__ BT, float* __restrict__ Cf)
{
  __shared__ unsigned short As[128 * 64];
  __shared__ unsigned short Bs[128 * 64];
  gemm_body<1>(A, BT, nullptr, Cf, 768, 768, As, Bs,
               (int)blockIdx.x * 128, (int)blockIdx.y * 128, (int)threadIdx.x);
}

// -------- fused per-expert FFN: Y[be][k][dh] = gate * (silu(gather(x1)@w1) @ w2), bf16 ----
// grid (8 m-tiles of 128 rows, 192 be). block 256. LDS exactly 80 KB -> 2 blocks/CU.
// All LDS XOR-chunk-swizzled (16B chunks): As/W1c pos = chunk^(row&15); W2c pos = chunk^(row&7);
// Hc pos = chunk^(tokrow&7).
__global__ __launch_bounds__(256, 2) void k_ffn(const unsigned short* __restrict__ x1,
    const unsigned short* __restrict__ w1T, const unsigned short* __restrict__ w2T,
    const int* __restrict__ KidxAll, const float* __restrict__ GvalAll,
    unsigned short* __restrict__ Y)
{
  __shared__ unsigned short As[128 * 128];   // 32 KB [row][k]
  __shared__ unsigned short W1c[64 * 128];   // 16 KB [hcol][k]
  __shared__ unsigned short W2c[128 * 64];   // 16 KB [out][hchunk]
  __shared__ unsigned short Hc[128 * 64];    // 16 KB [tokrow][hcol]
  const int tid = threadIdx.x, lane = tid & 63, w = tid >> 6;
  const int tx = lane & 15, quad = lane >> 4;
  const int mt = blockIdx.x;
  const int be = blockIdx.y;
  const int b = be / 24, e = be % 24;
  const int* idx = KidxAll + (long)be * 1024 + mt * 128;
  const float* scl = GvalAll + (long)be * 1024 + mt * 128;
  const unsigned short* A   = x1  + (long)b * 6144 * 128;
  const unsigned short* w1e = w1T + (long)e * 384 * 128;
  const unsigned short* w2e = w2T + (long)e * 128 * 384;

  {
    const int r0 = w * 32;
#pragma unroll
    for (int i = 0; i < 8; i++){
      int rr = r0 + i * 4 + quad;
      int c = tx ^ (rr & 15);
      gll16(A + (long)idx[rr] * 128 + c * 8, &As[(r0 + i * 4) * 128], lane);
    }
  }

  floatx4 Yt[2][8];   // [mf out-tile][nf tokrow-tile]
  {
    floatx4 z4 = {0.f, 0.f, 0.f, 0.f};
#pragma unroll
    for (int i = 0; i < 2; i++)
#pragma unroll
      for (int j = 0; j < 8; j++) Yt[i][j] = z4;
  }

  for (int nc = 0; nc < 6; ++nc){
    {
      const int r0 = w * 16;
#pragma unroll
      for (int i = 0; i < 4; i++){
        int lr = r0 + i * 4 + quad;
        int c = tx ^ (lr & 15);
        gll16(w1e + (long)(nc * 64 + lr) * 128 + c * 8, &W1c[(r0 + i * 4) * 128], lane);
      }
    }
    {
      const int r0 = w * 32;
#pragma unroll
      for (int i = 0; i < 4; i++){
        int rr = r0 + i * 8 + (lane >> 3);
        int c = (lane & 7) ^ (rr & 7);
        gll16(w2e + (long)rr * 384 + nc * 64 + c * 8, &W2c[(r0 + i * 8) * 64], lane);
      }
    }
    __syncthreads();

    // stage1: h = silu(As @ W1c^T); wave w -> rows w*32..+32 (2 mi) x 64 hcols (4 nf)
    floatx4 h4[2][4];
    {
      floatx4 z4 = {0.f, 0.f, 0.f, 0.f};
#pragma unroll
      for (int i = 0; i < 2; i++)
#pragma unroll
        for (int j = 0; j < 4; j++) h4[i][j] = z4;
    }
#pragma unroll
    for (int ks = 0; ks < 4; ++ks){
      const int chunk = ks * 4 + quad;
      const int pos = chunk ^ tx;
      short8 af[2];
#pragma unroll
      for (int mi = 0; mi < 2; ++mi)
        af[mi] = *(const short8*)&As[(w * 32 + mi * 16 + tx) * 128 + pos * 8];
#pragma unroll
      for (int nf = 0; nf < 4; ++nf){
        short8 bfr = *(const short8*)&W1c[(nf * 16 + tx) * 128 + pos * 8];
#pragma unroll
        for (int mi = 0; mi < 2; ++mi)
          h4[mi][nf] = __builtin_amdgcn_mfma_f32_16x16x32_bf16(af[mi], bfr, h4[mi][nf], 0, 0, 0);
      }
    }
#pragma unroll
    for (int mi = 0; mi < 2; ++mi){
#pragma unroll
      for (int nf = 0; nf < 4; ++nf){
        const int hchunk = nf * 2 + (tx >> 3);
        const int hoff = tx & 7;
#pragma unroll
        for (int r = 0; r < 4; r++){
          float v = silu(h4[mi][nf][r]);
          const int trow = w * 32 + mi * 16 + quad * 4 + r;
          Hc[trow * 64 + (hchunk ^ (trow & 7)) * 8 + hoff] = f2bf(v);
        }
      }
    }
    __syncthreads();

    // stage2: YT[out][tokrow] += W2c[out][hcol] x Hc[tokrow][hcol]; wave w -> outs w*32..+32
#pragma unroll
    for (int ks = 0; ks < 2; ++ks){
      const int chunk2 = ks * 4 + quad;
      const int posx = chunk2 ^ (tx & 7);
      short8 a2[2], b2[8];
#pragma unroll
      for (int mf = 0; mf < 2; ++mf)
        a2[mf] = *(const short8*)&W2c[(w * 32 + mf * 16 + tx) * 64 + posx * 8];
#pragma unroll
      for (int nf = 0; nf < 8; ++nf)
        b2[nf] = *(const short8*)&Hc[(nf * 16 + tx) * 64 + posx * 8];
#pragma unroll
      for (int mf = 0; mf < 2; ++mf)
#pragma unroll
        for (int nf = 0; nf < 8; ++nf)
          Yt[mf][nf] = __builtin_amdgcn_mfma_f32_16x16x32_bf16(a2[mf], b2[nf], Yt[mf][nf], 0, 0, 0);
    }
    __syncthreads();
  }

#pragma unroll
  for (int nf = 0; nf < 8; ++nf){
    const int rb = nf * 16 + tx;
    const float g = scl[rb];
    unsigned short* dst = Y + ((long)be * 1024 + mt * 128 + rb) * 128 + w * 32 + quad * 4;
#pragma unroll
    for (int mf = 0; mf < 2; ++mf){
      short4v v;
#pragma unroll
      for (int r = 0; r < 4; r++) v[r] = (short)f2bf(Yt[mf][nf][r] * g);
      *(short4v*)(dst + mf * 16) = v;
    }
  }
}

// -------- combine: xout[t][:] = sum over picks of Y[e][slot][:] (gates pre-applied) -------
__global__ __launch_bounds__(256) void k_combine(const int* __restrict__ cnt,
    const unsigned short* __restrict__ inv, const unsigned short* __restrict__ Y,
    unsigned short* __restrict__ xout)
{
  const int t = blockIdx.x * 4 + (threadIdx.x >> 6);   // token id, < 49152
  const int lane = threadIdx.x & 63;
  const int b = t / 6144;
  const int c = cnt[t];
  float a0 = 0.f, a1 = 0.f;
  for (int p = 0; p < c; ++p){
    int code = inv[(long)t * 24 + p];
    int e = code >> 10, slot = code & 1023;
    const unsigned short* y = Y + (((long)(b * 24 + e) * 1024 + slot) << 7) + lane * 2;
    a0 += bf2f(y[0]); a1 += bf2f(y[1]);
  }
  unsigned short* o = xout + ((long)t << 7) + lane * 2;
  o[0] = f2bf(a0); o[1] = f2bf(a1);
}

// ==========================================================================================
extern "C" void kernel_launch(void* const* d_in, const int* in_sizes, int n_in,
                              void* d_out, int out_size, void* d_ws, size_t ws_size,
                              hipStream_t stream)
{
  const float* x      = (const float*)d_in[0];
  const float* choice = (const float*)d_in[1];
  const float* w1     = (const float*)d_in[2];
  const float* w2     = (const float*)d_in[3];
  const float* head   = (const float*)d_in[4];
  const float* merge  = (const float*)d_in[5];
  float* out = (float*)d_out;
  (void)in_sizes; (void)n_in; (void)out_size; (void)ws_size;

  char* p = (char*)d_ws;
  auto alloc = [&p](size_t bytes) -> void* {
    void* q = (void*)p; p += (bytes + 255) & ~(size_t)255; return q;
  };

  unsigned short* headT = (unsigned short*)alloc((size_t)768 * 768 * 2);
  unsigned short* mergeT= (unsigned short*)alloc((size_t)768 * 768 * 2);
  unsigned short* w1T   = (unsigned short*)alloc((size_t)24 * 384 * 128 * 2);
  unsigned short* w2T   = (unsigned short*)alloc((size_t)24 * 128 * 384 * 2);
  double* W64           = (double*)alloc((size_t)768 * 144 * 8);
  int* Kidx             = (int*)alloc((size_t)192 * 1024 * 4);
  float* Gval           = (float*)alloc((size_t)192 * 1024 * 4);
  int* cnt              = (int*)alloc((size_t)49152 * 4);
  unsigned short* inv   = (unsigned short*)alloc((size_t)49152 * 24 * 2);
  unsigned short* xb    = (unsigned short*)alloc((size_t)8192 * 768 * 2);   // 12.58 MB
  unsigned short* x1    = (unsigned short*)alloc((size_t)8192 * 768 * 2);   // 12.58 MB
  // big region (50.33 MB): Y for ffn; before topk it hosts P (37.75) + gatesT (9.44)
  unsigned short* Y     = (unsigned short*)alloc((size_t)192 * 1024 * 128 * 2);
  double* P             = (double*)Y;                                             // [4][8192][144]
  double* gatesT        = (double*)((char*)Y + (size_t)4 * 8192 * 144 * 8);       // 9.44 MB
  unsigned short* xout  = xb;            // xb dead after k_main0; xout written by combine

  hipMemsetAsync(cnt, 0, (size_t)49152 * 4, stream);
  k_prep<<<dim3(7392), 256, 0, stream>>>(x, choice, w1, w2, head, merge,
                                         xb, headT, mergeT, w1T, w2T, W64);
  k_main0<<<dim3(1408), 256, 0, stream>>>(xb, headT, x1, x, W64, P);
  k_softmax<<<dim3(192), 256, 0, stream>>>(P, gatesT);
  k_topk<<<dim3(192), 256, 0, stream>>>(gatesT, Kidx, Gval, cnt, inv);
  // P/gatesT dead; Y region free for ffn
  k_ffn<<<dim3(8, 192, 1), 256, 0, stream>>>(x1, w1T, w2T, Kidx, Gval, Y);
  k_combine<<<dim3(12288), 256, 0, stream>>>(cnt, inv, Y, xout);
  k_gemm2<<<dim3(64, 6, 1), 256, 0, stream>>>(xout, mergeT, out);
}